// Round 1
// baseline (967.637 us; speedup 1.0000x reference)
//
#include <hip/hip_runtime.h>
#include <math.h>

#define N_NODES 100000
#define N_EDGES 1600000
#define E_TOT   (N_EDGES + N_NODES)
#define BN_EPS  1e-5f
#define NEG_SLOPE 0.2f

// ---------------------------------------------------------------- CSR build

__global__ __launch_bounds__(256) void k_count(const int* __restrict__ ei,
                                               int* __restrict__ cnt) {
    int i = blockIdx.x * blockDim.x + threadIdx.x;
    if (i >= E_TOT) return;
    int d = (i < N_EDGES) ? ei[N_EDGES + i] : (i - N_EDGES);
    atomicAdd(&cnt[d], 1);
}

// block scans 1024 elements (4/thread); writes per-block-exclusive into excl,
// block total into sums[blockIdx]
__global__ __launch_bounds__(256) void k_scan1(const int* __restrict__ cnt,
                                               int* __restrict__ excl,
                                               int* __restrict__ sums) {
    __shared__ int lds[256];
    int t = threadIdx.x;
    int base = blockIdx.x * 1024 + t * 4;
    int a[4];
#pragma unroll
    for (int j = 0; j < 4; ++j) a[j] = (base + j < N_NODES) ? cnt[base + j] : 0;
    int tot = a[0] + a[1] + a[2] + a[3];
    lds[t] = tot;
    __syncthreads();
    for (int off = 1; off < 256; off <<= 1) {
        int v = (t >= off) ? lds[t - off] : 0;
        __syncthreads();
        lds[t] += v;
        __syncthreads();
    }
    int run = lds[t] - tot;  // exclusive of thread-chunk
#pragma unroll
    for (int j = 0; j < 4; ++j) {
        if (base + j < N_NODES) excl[base + j] = run;
        run += a[j];
    }
    if (t == 255) sums[blockIdx.x] = lds[255];
}

__global__ void k_scan2(int* sums, int nb) {
    if (blockIdx.x == 0 && threadIdx.x == 0) {
        int run = 0;
        for (int i = 0; i < nb; ++i) { int v = sums[i]; sums[i] = run; run += v; }
    }
}

__global__ __launch_bounds__(256) void k_scan3(int* __restrict__ row_ptr,
                                               int* __restrict__ cursor,
                                               const int* __restrict__ sums) {
    int i = blockIdx.x * blockDim.x + threadIdx.x;
    if (i == 0) row_ptr[N_NODES] = E_TOT;
    if (i >= N_NODES) return;
    int v = row_ptr[i] + sums[i >> 10];
    row_ptr[i] = v;
    cursor[i] = v;
}

__global__ __launch_bounds__(256) void k_scatter(const int* __restrict__ ei,
                                                 int* __restrict__ cursor,
                                                 int* __restrict__ col_idx) {
    int i = blockIdx.x * blockDim.x + threadIdx.x;
    if (i >= E_TOT) return;
    int s, d;
    if (i < N_EDGES) { s = ei[i]; d = ei[N_EDGES + i]; }
    else             { s = d = i - N_EDGES; }
    int pos = atomicAdd(&cursor[d], 1);
    col_idx[pos] = s;
}

// ---------------------------------------------------------------- GEMM
// X[nrows,K] @ W[K,NC] -> Hout[nrows,NC].  Tile: BM rows/block, all NC cols.
// Thread (tx,ty): tx = col-group of 4, ty picks RPT consecutive rows.
template <int K, int NC, int BM, int BLOCK>
__global__ __launch_bounds__(BLOCK) void k_gemm(const float* __restrict__ X,
                                                const float* __restrict__ W,
                                                float* __restrict__ Hout,
                                                int nrows) {
    constexpr int CG  = NC / 4;
    constexpr int TR  = BLOCK / CG;
    constexpr int RPT = BM / TR;
    constexpr int LDK = K + 4;  // pad to avoid LDS bank conflicts
    __shared__ float xs[BM * LDK];
    const int row0 = blockIdx.x * BM;
    const int vr = (nrows - row0 < BM) ? (nrows - row0) : BM;
    const int nvalid = vr * K;
    for (int i = threadIdx.x * 4; i < BM * K; i += BLOCK * 4) {
        float4 v = make_float4(0.f, 0.f, 0.f, 0.f);
        if (i < nvalid) v = *(const float4*)(X + (size_t)row0 * K + i);
        int row = i / K, col = i % K;
        *(float4*)(&xs[row * LDK + col]) = v;
    }
    __syncthreads();
    const int tx = threadIdx.x % CG;
    const int ty = threadIdx.x / CG;
    float4 acc[RPT];
#pragma unroll
    for (int r = 0; r < RPT; ++r) acc[r] = make_float4(0.f, 0.f, 0.f, 0.f);
    for (int k4 = 0; k4 < K / 4; ++k4) {
        const float4 w0 = *(const float4*)(W + (k4 * 4 + 0) * NC + tx * 4);
        const float4 w1 = *(const float4*)(W + (k4 * 4 + 1) * NC + tx * 4);
        const float4 w2 = *(const float4*)(W + (k4 * 4 + 2) * NC + tx * 4);
        const float4 w3 = *(const float4*)(W + (k4 * 4 + 3) * NC + tx * 4);
#pragma unroll
        for (int r = 0; r < RPT; ++r) {
            const float4 xv = *(const float4*)(&xs[(ty * RPT + r) * LDK + k4 * 4]);
            acc[r].x = fmaf(xv.w, w3.x, fmaf(xv.z, w2.x, fmaf(xv.y, w1.x, fmaf(xv.x, w0.x, acc[r].x))));
            acc[r].y = fmaf(xv.w, w3.y, fmaf(xv.z, w2.y, fmaf(xv.y, w1.y, fmaf(xv.x, w0.y, acc[r].y))));
            acc[r].z = fmaf(xv.w, w3.z, fmaf(xv.z, w2.z, fmaf(xv.y, w1.z, fmaf(xv.x, w0.z, acc[r].z))));
            acc[r].w = fmaf(xv.w, w3.w, fmaf(xv.z, w2.w, fmaf(xv.y, w1.w, fmaf(xv.x, w0.w, acc[r].w))));
        }
    }
#pragma unroll
    for (int r = 0; r < RPT; ++r) {
        int row = row0 + ty * RPT + r;
        if (row < nrows) *(float4*)(Hout + (size_t)row * NC + tx * 4) = acc[r];
    }
}

// ---------------------------------------------------------------- attention projections

// layer1: F=128, H=4, C=32.  wave per node; lane covers features lane, lane+64.
__global__ __launch_bounds__(256) void k_attproj1(const float* __restrict__ h,
                                                  const float* __restrict__ asf,
                                                  const float* __restrict__ adf,
                                                  float* __restrict__ a_s,
                                                  float* __restrict__ a_d) {
    int wv = (blockIdx.x * blockDim.x + threadIdx.x) >> 6;
    int lane = threadIdx.x & 63;
    if (wv >= N_NODES) return;
    float hlo = h[(size_t)wv * 128 + lane];
    float hhi = h[(size_t)wv * 128 + 64 + lane];
    float s0 = hlo * asf[lane], s1 = hhi * asf[64 + lane];
    float d0 = hlo * adf[lane], d1 = hhi * adf[64 + lane];
#pragma unroll
    for (int off = 1; off < 32; off <<= 1) {
        s0 += __shfl_xor(s0, off); s1 += __shfl_xor(s1, off);
        d0 += __shfl_xor(d0, off); d1 += __shfl_xor(d1, off);
    }
    if (lane == 0)  { a_s[wv * 4 + 0] = s0; a_s[wv * 4 + 2] = s1;
                      a_d[wv * 4 + 0] = d0; a_d[wv * 4 + 2] = d1; }
    if (lane == 32) { a_s[wv * 4 + 1] = s0; a_s[wv * 4 + 3] = s1;
                      a_d[wv * 4 + 1] = d0; a_d[wv * 4 + 3] = d1; }
}

// layer2: F=32, 1 head. wave handles 2 nodes.
__global__ __launch_bounds__(256) void k_attproj2(const float* __restrict__ h,
                                                  const float* __restrict__ asf,
                                                  const float* __restrict__ adf,
                                                  float* __restrict__ a_s,
                                                  float* __restrict__ a_d) {
    int wv = (blockIdx.x * blockDim.x + threadIdx.x) >> 6;
    int lane = threadIdx.x & 63;
    if (wv * 2 >= N_NODES) return;
    int n = wv * 2 + (lane >> 5);
    int l = lane & 31;
    float hv = h[(size_t)n * 32 + l];
    float s = hv * asf[l], d = hv * adf[l];
#pragma unroll
    for (int off = 1; off < 32; off <<= 1) { s += __shfl_xor(s, off); d += __shfl_xor(d, off); }
    if (l == 0) { a_s[n] = s; a_d[n] = d; }
}

// layer3: F=40, 1 head. wave per node; lanes >=40 contribute zero.
__global__ __launch_bounds__(256) void k_attproj3(const float* __restrict__ h,
                                                  const float* __restrict__ asf,
                                                  const float* __restrict__ adf,
                                                  float* __restrict__ a_s,
                                                  float* __restrict__ a_d) {
    int wv = (blockIdx.x * blockDim.x + threadIdx.x) >> 6;
    int lane = threadIdx.x & 63;
    if (wv >= N_NODES) return;
    float hv = (lane < 40) ? h[(size_t)wv * 40 + lane] : 0.f;
    float s = (lane < 40) ? hv * asf[lane] : 0.f;
    float d = (lane < 40) ? hv * adf[lane] : 0.f;
#pragma unroll
    for (int off = 1; off < 64; off <<= 1) { s += __shfl_xor(s, off); d += __shfl_xor(d, off); }
    if (lane == 0) { a_s[wv] = s; a_d[wv] = d; }
}

// ---------------------------------------------------------------- aggregation

// layer1: H=4, C=32. wave per dst node; lane covers features lane (head lane/32)
// and lane+64 (head 2+lane/32). Online softmax per head, fused bias+BN+ELU.
__global__ __launch_bounds__(256) void k_agg1(const float* __restrict__ h,
                                              const float* __restrict__ a_s,
                                              const float* __restrict__ a_d,
                                              const int* __restrict__ row_ptr,
                                              const int* __restrict__ col_idx,
                                              const float* __restrict__ b,
                                              const float* __restrict__ g,
                                              const float* __restrict__ beta,
                                              const float* __restrict__ rm,
                                              const float* __restrict__ rv,
                                              float* __restrict__ obuf) {
    int n = (blockIdx.x * blockDim.x + threadIdx.x) >> 6;
    int lane = threadIdx.x & 63;
    if (n >= N_NODES) return;
    const int hi = lane >> 5;  // 0 or 1
    float4 ad4 = *(const float4*)(a_d + n * 4);
    float ad0 = hi ? ad4.y : ad4.x;
    float ad1 = hi ? ad4.w : ad4.z;
    int beg = row_ptr[n], end = row_ptr[n + 1];
    float m0 = -INFINITY, m1 = -INFINITY, den0 = 0.f, den1 = 0.f, acc0 = 0.f, acc1 = 0.f;
    for (int e = beg; e < end; ++e) {
        int s = col_idx[e];
        float4 as4 = *(const float4*)(a_s + s * 4);
        float e0 = (hi ? as4.y : as4.x) + ad0;
        float e1 = (hi ? as4.w : as4.z) + ad1;
        e0 = e0 > 0.f ? e0 : NEG_SLOPE * e0;
        e1 = e1 > 0.f ? e1 : NEG_SLOPE * e1;
        float hlo = h[(size_t)s * 128 + lane];
        float hhi = h[(size_t)s * 128 + 64 + lane];
        float nm0 = fmaxf(m0, e0), nm1 = fmaxf(m1, e1);
        float sc0 = __expf(m0 - nm0), sc1 = __expf(m1 - nm1);
        float p0 = __expf(e0 - nm0), p1 = __expf(e1 - nm1);
        den0 = den0 * sc0 + p0;  acc0 = acc0 * sc0 + p0 * hlo;  m0 = nm0;
        den1 = den1 * sc1 + p1;  acc1 = acc1 * sc1 + p1 * hhi;  m1 = nm1;
    }
    float f0 = acc0 / (den0 + 1e-16f);
    float f1 = acc1 / (den1 + 1e-16f);
    int fA = lane, fB = lane + 64;
    f0 += b[fA]; f1 += b[fB];
    f0 = (f0 - rm[fA]) * rsqrtf(rv[fA] + BN_EPS) * g[fA] + beta[fA];
    f1 = (f1 - rm[fB]) * rsqrtf(rv[fB] + BN_EPS) * g[fB] + beta[fB];
    f0 = f0 > 0.f ? f0 : (__expf(f0) - 1.f);
    f1 = f1 > 0.f ? f1 : (__expf(f1) - 1.f);
    obuf[(size_t)n * 128 + fA] = f0;
    obuf[(size_t)n * 128 + fB] = f1;
}

// layer2: 1 head, C=32. wave handles 2 nodes (one per 32-lane half).
__global__ __launch_bounds__(256) void k_agg2(const float* __restrict__ h,
                                              const float* __restrict__ a_s,
                                              const float* __restrict__ a_d,
                                              const int* __restrict__ row_ptr,
                                              const int* __restrict__ col_idx,
                                              const float* __restrict__ b,
                                              const float* __restrict__ g,
                                              const float* __restrict__ beta,
                                              const float* __restrict__ rm,
                                              const float* __restrict__ rv,
                                              float* __restrict__ obuf) {
    int wv = (blockIdx.x * blockDim.x + threadIdx.x) >> 6;
    int lane = threadIdx.x & 63;
    if (wv * 2 >= N_NODES) return;
    int n = wv * 2 + (lane >> 5);
    int l = lane & 31;
    float ad = a_d[n];
    int beg = row_ptr[n], end = row_ptr[n + 1];
    float m = -INFINITY, den = 0.f, acc = 0.f;
    for (int e = beg; e < end; ++e) {
        int s = col_idx[e];
        float es = a_s[s] + ad;
        es = es > 0.f ? es : NEG_SLOPE * es;
        float hv = h[(size_t)s * 32 + l];
        float nm = fmaxf(m, es);
        float sc = __expf(m - nm), p = __expf(es - nm);
        den = den * sc + p; acc = acc * sc + p * hv; m = nm;
    }
    float v = acc / (den + 1e-16f);
    v += b[l];
    v = (v - rm[l]) * rsqrtf(rv[l] + BN_EPS) * g[l] + beta[l];
    v = v > 0.f ? v : (__expf(v) - 1.f);
    obuf[(size_t)n * 32 + l] = v;
}

// layer3: 1 head, C=40. wave per node; fused bias + log_softmax.
__global__ __launch_bounds__(256) void k_agg3(const float* __restrict__ h,
                                              const float* __restrict__ a_s,
                                              const float* __restrict__ a_d,
                                              const int* __restrict__ row_ptr,
                                              const int* __restrict__ col_idx,
                                              const float* __restrict__ b,
                                              float* __restrict__ out) {
    int n = (blockIdx.x * blockDim.x + threadIdx.x) >> 6;
    int lane = threadIdx.x & 63;
    if (n >= N_NODES) return;
    float ad = a_d[n];
    int beg = row_ptr[n], end = row_ptr[n + 1];
    float m = -INFINITY, den = 0.f, acc = 0.f;
    for (int e = beg; e < end; ++e) {
        int s = col_idx[e];
        float es = a_s[s] + ad;
        es = es > 0.f ? es : NEG_SLOPE * es;
        float hv = (lane < 40) ? h[(size_t)s * 40 + lane] : 0.f;
        float nm = fmaxf(m, es);
        float sc = __expf(m - nm), p = __expf(es - nm);
        den = den * sc + p; acc = acc * sc + p * hv; m = nm;
    }
    float v = acc / (den + 1e-16f) + b[lane < 40 ? lane : 0];
    float vm = (lane < 40) ? v : -INFINITY;
#pragma unroll
    for (int off = 1; off < 64; off <<= 1) vm = fmaxf(vm, __shfl_xor(vm, off));
    float ex = (lane < 40) ? __expf(v - vm) : 0.f;
#pragma unroll
    for (int off = 1; off < 64; off <<= 1) ex += __shfl_xor(ex, off);
    float res = v - vm - logf(ex);
    if (lane < 40) out[(size_t)n * 40 + lane] = res;
}

// ---------------------------------------------------------------- launch

extern "C" void kernel_launch(void* const* d_in, const int* in_sizes, int n_in,
                              void* d_out, int out_size, void* d_ws, size_t ws_size,
                              hipStream_t stream) {
    const float* x    = (const float*)d_in[0];
    const int*   ei   = (const int*)d_in[1];
    const float* W1   = (const float*)d_in[2];
    const float* as1  = (const float*)d_in[3];
    const float* ad1  = (const float*)d_in[4];
    const float* b1   = (const float*)d_in[5];
    const float* g1   = (const float*)d_in[6];
    const float* be1  = (const float*)d_in[7];
    const float* rm1  = (const float*)d_in[8];
    const float* rv1  = (const float*)d_in[9];
    const float* W2   = (const float*)d_in[10];
    const float* as2  = (const float*)d_in[11];
    const float* ad2  = (const float*)d_in[12];
    const float* b2   = (const float*)d_in[13];
    const float* g2   = (const float*)d_in[14];
    const float* be2  = (const float*)d_in[15];
    const float* rm2  = (const float*)d_in[16];
    const float* rv2  = (const float*)d_in[17];
    const float* W3   = (const float*)d_in[18];
    const float* as3  = (const float*)d_in[19];
    const float* ad3  = (const float*)d_in[20];
    const float* b3   = (const float*)d_in[21];
    float* out = (float*)d_out;

    // workspace carve-up (256B aligned)
    char* base = (char*)d_ws;
    size_t off = 0;
    auto carve = [&](size_t bytes) {
        char* p = base + off;
        off = (off + bytes + 255) & ~(size_t)255;
        return p;
    };
    int*   row_ptr = (int*)carve((N_NODES + 1) * sizeof(int));
    int*   cnt     = (int*)carve(N_NODES * sizeof(int));
    int*   cursor  = (int*)carve(N_NODES * sizeof(int));
    int*   sums    = (int*)carve(1024 * sizeof(int));
    int*   col_idx = (int*)carve((size_t)E_TOT * sizeof(int));
    float* a_s     = (float*)carve((size_t)N_NODES * 4 * sizeof(float));
    float* a_d     = (float*)carve((size_t)N_NODES * 4 * sizeof(float));
    float* hbuf    = (float*)carve((size_t)N_NODES * 128 * sizeof(float));
    float* obuf    = (float*)carve((size_t)N_NODES * 128 * sizeof(float));
    (void)ws_size;

    // ---- CSR build (dst-sorted)
    hipMemsetAsync(cnt, 0, N_NODES * sizeof(int), stream);
    {
        int g1b = (E_TOT + 255) / 256;
        k_count<<<g1b, 256, 0, stream>>>(ei, cnt);
        int nb = (N_NODES + 1023) / 1024;
        k_scan1<<<nb, 256, 0, stream>>>(cnt, row_ptr, sums);
        k_scan2<<<1, 1, 0, stream>>>(sums, nb);
        k_scan3<<<(N_NODES + 255) / 256, 256, 0, stream>>>(row_ptr, cursor, sums);
        k_scatter<<<g1b, 256, 0, stream>>>(ei, cursor, col_idx);
    }

    const int GEMM_GRID = (N_NODES + 63) / 64;
    const int WPN   = (N_NODES + 3) / 4;       // wave-per-node kernels, 4 waves/block
    const int WP2N  = (N_NODES / 2 + 3) / 4;   // 2-nodes-per-wave kernels

    // ---- layer 1
    k_gemm<128, 128, 64, 256><<<GEMM_GRID, 256, 0, stream>>>(x, W1, hbuf, N_NODES);
    k_attproj1<<<WPN, 256, 0, stream>>>(hbuf, as1, ad1, a_s, a_d);
    k_agg1<<<WPN, 256, 0, stream>>>(hbuf, a_s, a_d, row_ptr, col_idx,
                                    b1, g1, be1, rm1, rv1, obuf);
    // ---- layer 2
    k_gemm<128, 32, 64, 256><<<GEMM_GRID, 256, 0, stream>>>(obuf, W2, hbuf, N_NODES);
    k_attproj2<<<WP2N, 256, 0, stream>>>(hbuf, as2, ad2, a_s, a_d);
    k_agg2<<<WP2N, 256, 0, stream>>>(hbuf, a_s, a_d, row_ptr, col_idx,
                                     b2, g2, be2, rm2, rv2, obuf);
    // ---- layer 3
    k_gemm<32, 40, 64, 320><<<GEMM_GRID, 320, 0, stream>>>(obuf, W3, hbuf, N_NODES);
    k_attproj3<<<WPN, 256, 0, stream>>>(hbuf, as3, ad3, a_s, a_d);
    k_agg3<<<WPN, 256, 0, stream>>>(hbuf, a_s, a_d, row_ptr, col_idx, b3, out);
}

// Round 5
// 785.320 us; speedup vs baseline: 1.2322x; 1.2322x over previous
//
#include <hip/hip_runtime.h>
#include <math.h>

#define N_NODES 100000
#define N_EDGES 1600000
#define E_TOT   (N_EDGES + N_NODES)
#define BN_EPS  1e-5f
#define NEG_SLOPE 0.2f
#define NINF (-INFINITY)

// ---------------------------------------------------------------- CSR build

__global__ __launch_bounds__(256) void k_count(const int* __restrict__ ei,
                                               int* __restrict__ cnt) {
    int i = blockIdx.x * blockDim.x + threadIdx.x;
    if (i >= E_TOT) return;
    int d = (i < N_EDGES) ? ei[N_EDGES + i] : (i - N_EDGES);
    atomicAdd(&cnt[d], 1);
}

__global__ __launch_bounds__(256) void k_scan1(const int* __restrict__ cnt,
                                               int* __restrict__ excl,
                                               int* __restrict__ sums) {
    __shared__ int lds[256];
    int t = threadIdx.x;
    int base = blockIdx.x * 1024 + t * 4;
    int a[4];
#pragma unroll
    for (int j = 0; j < 4; ++j) a[j] = (base + j < N_NODES) ? cnt[base + j] : 0;
    int tot = a[0] + a[1] + a[2] + a[3];
    lds[t] = tot;
    __syncthreads();
    for (int off = 1; off < 256; off <<= 1) {
        int v = (t >= off) ? lds[t - off] : 0;
        __syncthreads();
        lds[t] += v;
        __syncthreads();
    }
    int run = lds[t] - tot;
#pragma unroll
    for (int j = 0; j < 4; ++j) {
        if (base + j < N_NODES) excl[base + j] = run;
        run += a[j];
    }
    if (t == 255) sums[blockIdx.x] = lds[255];
}

__global__ void k_scan2(int* sums, int nb) {
    if (blockIdx.x == 0 && threadIdx.x == 0) {
        int run = 0;
        for (int i = 0; i < nb; ++i) { int v = sums[i]; sums[i] = run; run += v; }
    }
}

__global__ __launch_bounds__(256) void k_scan3(int* __restrict__ row_ptr,
                                               int* __restrict__ cursor,
                                               const int* __restrict__ sums) {
    int i = blockIdx.x * blockDim.x + threadIdx.x;
    if (i == 0) row_ptr[N_NODES] = E_TOT;
    if (i >= N_NODES) return;
    int v = row_ptr[i] + sums[i >> 10];
    row_ptr[i] = v;
    cursor[i] = v;
}

__global__ __launch_bounds__(256) void k_scatter(const int* __restrict__ ei,
                                                 int* __restrict__ cursor,
                                                 int* __restrict__ col_idx) {
    int i = blockIdx.x * blockDim.x + threadIdx.x;
    if (i >= E_TOT) return;
    int s, d;
    if (i < N_EDGES) { s = ei[i]; d = ei[N_EDGES + i]; }
    else             { s = d = i - N_EDGES; }
    int pos = atomicAdd(&cursor[d], 1);
    col_idx[pos] = s;
}

// ---------------------------------------------------------------- GEMM

template <int K, int NC, int BM, int BLOCK>
__global__ __launch_bounds__(BLOCK) void k_gemm(const float* __restrict__ X,
                                                const float* __restrict__ W,
                                                float* __restrict__ Hout,
                                                int nrows) {
    constexpr int CG  = NC / 4;
    constexpr int TR  = BLOCK / CG;
    constexpr int RPT = BM / TR;
    constexpr int LDK = K + 4;
    __shared__ float xs[BM * LDK];
    const int row0 = blockIdx.x * BM;
    const int vr = (nrows - row0 < BM) ? (nrows - row0) : BM;
    const int nvalid = vr * K;
    for (int i = threadIdx.x * 4; i < BM * K; i += BLOCK * 4) {
        float4 v = make_float4(0.f, 0.f, 0.f, 0.f);
        if (i < nvalid) v = *(const float4*)(X + (size_t)row0 * K + i);
        int row = i / K, col = i % K;
        *(float4*)(&xs[row * LDK + col]) = v;
    }
    __syncthreads();
    const int tx = threadIdx.x % CG;
    const int ty = threadIdx.x / CG;
    float4 acc[RPT];
#pragma unroll
    for (int r = 0; r < RPT; ++r) acc[r] = make_float4(0.f, 0.f, 0.f, 0.f);
    for (int k4 = 0; k4 < K / 4; ++k4) {
        const float4 w0 = *(const float4*)(W + (k4 * 4 + 0) * NC + tx * 4);
        const float4 w1 = *(const float4*)(W + (k4 * 4 + 1) * NC + tx * 4);
        const float4 w2 = *(const float4*)(W + (k4 * 4 + 2) * NC + tx * 4);
        const float4 w3 = *(const float4*)(W + (k4 * 4 + 3) * NC + tx * 4);
#pragma unroll
        for (int r = 0; r < RPT; ++r) {
            const float4 xv = *(const float4*)(&xs[(ty * RPT + r) * LDK + k4 * 4]);
            acc[r].x = fmaf(xv.w, w3.x, fmaf(xv.z, w2.x, fmaf(xv.y, w1.x, fmaf(xv.x, w0.x, acc[r].x))));
            acc[r].y = fmaf(xv.w, w3.y, fmaf(xv.z, w2.y, fmaf(xv.y, w1.y, fmaf(xv.x, w0.y, acc[r].y))));
            acc[r].z = fmaf(xv.w, w3.z, fmaf(xv.z, w2.z, fmaf(xv.y, w1.z, fmaf(xv.x, w0.z, acc[r].z))));
            acc[r].w = fmaf(xv.w, w3.w, fmaf(xv.z, w2.w, fmaf(xv.y, w1.w, fmaf(xv.x, w0.w, acc[r].w))));
        }
    }
#pragma unroll
    for (int r = 0; r < RPT; ++r) {
        int row = row0 + ty * RPT + r;
        if (row < nrows) *(float4*)(Hout + (size_t)row * NC + tx * 4) = acc[r];
    }
}

// ---------------------------------------------------------------- attention projections

__global__ __launch_bounds__(256) void k_attproj1(const float* __restrict__ h,
                                                  const float* __restrict__ asf,
                                                  const float* __restrict__ adf,
                                                  float* __restrict__ a_s,
                                                  float* __restrict__ a_d) {
    int wv = (blockIdx.x * blockDim.x + threadIdx.x) >> 6;
    int lane = threadIdx.x & 63;
    if (wv >= N_NODES) return;
    float hlo = h[(size_t)wv * 128 + lane];
    float hhi = h[(size_t)wv * 128 + 64 + lane];
    float s0 = hlo * asf[lane], s1 = hhi * asf[64 + lane];
    float d0 = hlo * adf[lane], d1 = hhi * adf[64 + lane];
#pragma unroll
    for (int off = 1; off < 32; off <<= 1) {
        s0 += __shfl_xor(s0, off); s1 += __shfl_xor(s1, off);
        d0 += __shfl_xor(d0, off); d1 += __shfl_xor(d1, off);
    }
    if (lane == 0)  { a_s[wv * 4 + 0] = s0; a_s[wv * 4 + 2] = s1;
                      a_d[wv * 4 + 0] = d0; a_d[wv * 4 + 2] = d1; }
    if (lane == 32) { a_s[wv * 4 + 1] = s0; a_s[wv * 4 + 3] = s1;
                      a_d[wv * 4 + 1] = d0; a_d[wv * 4 + 3] = d1; }
}

__global__ __launch_bounds__(256) void k_attproj2(const float* __restrict__ h,
                                                  const float* __restrict__ asf,
                                                  const float* __restrict__ adf,
                                                  float* __restrict__ a_s,
                                                  float* __restrict__ a_d) {
    int wv = (blockIdx.x * blockDim.x + threadIdx.x) >> 6;
    int lane = threadIdx.x & 63;
    if (wv * 2 >= N_NODES) return;
    int n = wv * 2 + (lane >> 5);
    int l = lane & 31;
    float hv = h[(size_t)n * 32 + l];
    float s = hv * asf[l], d = hv * adf[l];
#pragma unroll
    for (int off = 1; off < 32; off <<= 1) { s += __shfl_xor(s, off); d += __shfl_xor(d, off); }
    if (l == 0) { a_s[n] = s; a_d[n] = d; }
}

__global__ __launch_bounds__(256) void k_attproj3(const float* __restrict__ h,
                                                  const float* __restrict__ asf,
                                                  const float* __restrict__ adf,
                                                  float* __restrict__ a_s,
                                                  float* __restrict__ a_d) {
    int wv = (blockIdx.x * blockDim.x + threadIdx.x) >> 6;
    int lane = threadIdx.x & 63;
    if (wv >= N_NODES) return;
    float hv = (lane < 40) ? h[(size_t)wv * 40 + lane] : 0.f;
    float s = (lane < 40) ? hv * asf[lane] : 0.f;
    float d = (lane < 40) ? hv * adf[lane] : 0.f;
#pragma unroll
    for (int off = 1; off < 64; off <<= 1) { s += __shfl_xor(s, off); d += __shfl_xor(d, off); }
    if (lane == 0) { a_s[wv] = s; a_d[wv] = d; }
}

// ---------------------------------------------------------------- aggregation
// Two-phase per node: (1) lane-parallel softmax over edges — e computed once
// per edge, p/col parked in per-wave LDS; (2) pure-FMA gather loop with LDS
// broadcast reads, no transcendentals.

// layer1: H=4, C=32 (128 feats). 1 wave/node; lane owns feats lane, lane+64.
__global__ __launch_bounds__(256) void k_agg1(const float* __restrict__ h,
                                              const float* __restrict__ a_s,
                                              const float* __restrict__ a_d,
                                              const int* __restrict__ row_ptr,
                                              const int* __restrict__ col_idx,
                                              const float* __restrict__ b,
                                              const float* __restrict__ g,
                                              const float* __restrict__ beta,
                                              const float* __restrict__ rm,
                                              const float* __restrict__ rv,
                                              float* __restrict__ obuf) {
    __shared__ float4 lp[4 * 64];
    __shared__ int    lc[4 * 64];
    const int wid  = threadIdx.x >> 6;
    const int lane = threadIdx.x & 63;
    const int n = (blockIdx.x << 2) + wid;
    if (n >= N_NODES) return;
    float4* lpw = lp + (wid << 6);
    int*    lcw = lc + (wid << 6);
    const int hi = lane >> 5;
    const float4 ad4 = *(const float4*)(a_d + (size_t)n * 4);
    const int beg = row_ptr[n], end = row_ptr[n + 1];
    const int deg = end - beg;
    float den0 = 0.f, den1 = 0.f, den2 = 0.f, den3 = 0.f;
    float acc0 = 0.f, acc1 = 0.f;

    if (deg <= 64) {
        const int idx = beg + lane;
        const bool v = idx < end;
        const int col = v ? col_idx[idx] : 0;
        float e0, e1, e2, e3;
        if (v) {
            float4 as4 = *(const float4*)(a_s + (size_t)col * 4);
            e0 = as4.x + ad4.x; e0 = e0 > 0.f ? e0 : NEG_SLOPE * e0;
            e1 = as4.y + ad4.y; e1 = e1 > 0.f ? e1 : NEG_SLOPE * e1;
            e2 = as4.z + ad4.z; e2 = e2 > 0.f ? e2 : NEG_SLOPE * e2;
            e3 = as4.w + ad4.w; e3 = e3 > 0.f ? e3 : NEG_SLOPE * e3;
        } else { e0 = e1 = e2 = e3 = NINF; }
        float m0 = e0, m1 = e1, m2 = e2, m3 = e3;
#pragma unroll
        for (int off = 1; off < 64; off <<= 1) {
            m0 = fmaxf(m0, __shfl_xor(m0, off));
            m1 = fmaxf(m1, __shfl_xor(m1, off));
            m2 = fmaxf(m2, __shfl_xor(m2, off));
            m3 = fmaxf(m3, __shfl_xor(m3, off));
        }
        float p0 = __expf(e0 - m0), p1 = __expf(e1 - m1);
        float p2 = __expf(e2 - m2), p3 = __expf(e3 - m3);
        lpw[lane] = make_float4(p0, p1, p2, p3);
        lcw[lane] = col;
        den0 = p0; den1 = p1; den2 = p2; den3 = p3;
#pragma unroll
        for (int off = 1; off < 64; off <<= 1) {
            den0 += __shfl_xor(den0, off); den1 += __shfl_xor(den1, off);
            den2 += __shfl_xor(den2, off); den3 += __shfl_xor(den3, off);
        }
        const int cnt = (deg + 1) & ~1;
        for (int j = 0; j < cnt; j += 2) {
            float4 pa = lpw[j];
            float4 pb = lpw[j + 1];
            int c0 = lcw[j], c1 = lcw[j + 1];
            const float* r0 = h + (size_t)c0 * 128;
            const float* r1 = h + (size_t)c1 * 128;
            float h00 = r0[lane], h01 = r0[64 + lane];
            float h10 = r1[lane], h11 = r1[64 + lane];
            float pA0 = hi ? pa.y : pa.x, pB0 = hi ? pa.w : pa.z;
            float pA1 = hi ? pb.y : pb.x, pB1 = hi ? pb.w : pb.z;
            acc0 += pA0 * h00 + pA1 * h10;
            acc1 += pB0 * h01 + pB1 * h11;
        }
    } else {
        // slow path: chunked two-pass (deg > 64 is astronomically rare)
        float m0 = NINF, m1 = NINF, m2 = NINF, m3 = NINF;
        for (int c = beg; c < end; c += 64) {
            int idx = c + lane;
            bool v = idx < end;
            if (v) {
                int col = col_idx[idx];
                float4 as4 = *(const float4*)(a_s + (size_t)col * 4);
                float e0 = as4.x + ad4.x; e0 = e0 > 0.f ? e0 : NEG_SLOPE * e0;
                float e1 = as4.y + ad4.y; e1 = e1 > 0.f ? e1 : NEG_SLOPE * e1;
                float e2 = as4.z + ad4.z; e2 = e2 > 0.f ? e2 : NEG_SLOPE * e2;
                float e3 = as4.w + ad4.w; e3 = e3 > 0.f ? e3 : NEG_SLOPE * e3;
                m0 = fmaxf(m0, e0); m1 = fmaxf(m1, e1);
                m2 = fmaxf(m2, e2); m3 = fmaxf(m3, e3);
            }
        }
#pragma unroll
        for (int off = 1; off < 64; off <<= 1) {
            m0 = fmaxf(m0, __shfl_xor(m0, off));
            m1 = fmaxf(m1, __shfl_xor(m1, off));
            m2 = fmaxf(m2, __shfl_xor(m2, off));
            m3 = fmaxf(m3, __shfl_xor(m3, off));
        }
        for (int c = beg; c < end; c += 64) {
            int idx = c + lane;
            bool v = idx < end;
            int col = v ? col_idx[idx] : 0;
            float p0 = 0.f, p1 = 0.f, p2 = 0.f, p3 = 0.f;
            if (v) {
                float4 as4 = *(const float4*)(a_s + (size_t)col * 4);
                float e0 = as4.x + ad4.x; e0 = e0 > 0.f ? e0 : NEG_SLOPE * e0;
                float e1 = as4.y + ad4.y; e1 = e1 > 0.f ? e1 : NEG_SLOPE * e1;
                float e2 = as4.z + ad4.z; e2 = e2 > 0.f ? e2 : NEG_SLOPE * e2;
                float e3 = as4.w + ad4.w; e3 = e3 > 0.f ? e3 : NEG_SLOPE * e3;
                p0 = __expf(e0 - m0); p1 = __expf(e1 - m1);
                p2 = __expf(e2 - m2); p3 = __expf(e3 - m3);
            }
            lpw[lane] = make_float4(p0, p1, p2, p3);
            lcw[lane] = col;
            float s0 = p0, s1 = p1, s2 = p2, s3 = p3;
#pragma unroll
            for (int off = 1; off < 64; off <<= 1) {
                s0 += __shfl_xor(s0, off); s1 += __shfl_xor(s1, off);
                s2 += __shfl_xor(s2, off); s3 += __shfl_xor(s3, off);
            }
            den0 += s0; den1 += s1; den2 += s2; den3 += s3;
            int csz = end - c; if (csz > 64) csz = 64;
            int cnt = (csz + 1) & ~1;
            for (int j = 0; j < cnt; j += 2) {
                float4 pa = lpw[j];
                float4 pb = lpw[j + 1];
                int c0i = lcw[j], c1i = lcw[j + 1];
                const float* r0 = h + (size_t)c0i * 128;
                const float* r1 = h + (size_t)c1i * 128;
                float h00 = r0[lane], h01 = r0[64 + lane];
                float h10 = r1[lane], h11 = r1[64 + lane];
                float pA0 = hi ? pa.y : pa.x, pB0 = hi ? pa.w : pa.z;
                float pA1 = hi ? pb.y : pb.x, pB1 = hi ? pb.w : pb.z;
                acc0 += pA0 * h00 + pA1 * h10;
                acc1 += pB0 * h01 + pB1 * h11;
            }
        }
    }

    float inv0 = 1.f / (den0 + 1e-16f), inv1 = 1.f / (den1 + 1e-16f);
    float inv2 = 1.f / (den2 + 1e-16f), inv3 = 1.f / (den3 + 1e-16f);
    float f0 = acc0 * (hi ? inv1 : inv0);
    float f1 = acc1 * (hi ? inv3 : inv2);
    int fA = lane, fB = lane + 64;
    f0 += b[fA]; f1 += b[fB];
    f0 = (f0 - rm[fA]) * rsqrtf(rv[fA] + BN_EPS) * g[fA] + beta[fA];
    f1 = (f1 - rm[fB]) * rsqrtf(rv[fB] + BN_EPS) * g[fB] + beta[fB];
    f0 = f0 > 0.f ? f0 : (__expf(f0) - 1.f);
    f1 = f1 > 0.f ? f1 : (__expf(f1) - 1.f);
    obuf[(size_t)n * 128 + fA] = f0;
    obuf[(size_t)n * 128 + fB] = f1;
}

// layer2: 1 head, C=32. 1 wave/node; gather does 2 edges/iter (one per half),
// folded by shfl_xor(acc,32) at the end.
__global__ __launch_bounds__(256) void k_agg2(const float* __restrict__ h,
                                              const float* __restrict__ a_s,
                                              const float* __restrict__ a_d,
                                              const int* __restrict__ row_ptr,
                                              const int* __restrict__ col_idx,
                                              const float* __restrict__ b,
                                              const float* __restrict__ g,
                                              const float* __restrict__ beta,
                                              const float* __restrict__ rm,
                                              const float* __restrict__ rv,
                                              float* __restrict__ obuf) {
    __shared__ float lp[4 * 64];
    __shared__ int   lc[4 * 64];
    const int wid  = threadIdx.x >> 6;
    const int lane = threadIdx.x & 63;
    const int n = (blockIdx.x << 2) + wid;
    if (n >= N_NODES) return;
    float* lpw = lp + (wid << 6);
    int*   lcw = lc + (wid << 6);
    const int l31 = lane & 31, hh = lane >> 5;
    const float ad = a_d[n];
    const int beg = row_ptr[n], end = row_ptr[n + 1];
    const int deg = end - beg;
    float den = 0.f, acc = 0.f;

    if (deg <= 64) {
        const int idx = beg + lane;
        const bool v = idx < end;
        const int col = v ? col_idx[idx] : 0;
        float e = NINF;
        if (v) {
            e = a_s[col] + ad;
            e = e > 0.f ? e : NEG_SLOPE * e;
        }
        float m = e;
#pragma unroll
        for (int off = 1; off < 64; off <<= 1) m = fmaxf(m, __shfl_xor(m, off));
        float p = __expf(e - m);
        lpw[lane] = p;
        lcw[lane] = col;
        den = p;
#pragma unroll
        for (int off = 1; off < 64; off <<= 1) den += __shfl_xor(den, off);
        const int cnt = (deg + 1) & ~1;
        for (int j = 0; j < cnt; j += 2) {
            int jj = j + hh;
            float p_ = lpw[jj];
            int c  = lcw[jj];
            acc += p_ * h[(size_t)c * 32 + l31];
        }
    } else {
        float m = NINF;
        for (int c = beg; c < end; c += 64) {
            int idx = c + lane;
            if (idx < end) {
                float e = a_s[col_idx[idx]] + ad;
                e = e > 0.f ? e : NEG_SLOPE * e;
                m = fmaxf(m, e);
            }
        }
#pragma unroll
        for (int off = 1; off < 64; off <<= 1) m = fmaxf(m, __shfl_xor(m, off));
        for (int c = beg; c < end; c += 64) {
            int idx = c + lane;
            bool v = idx < end;
            int col = v ? col_idx[idx] : 0;
            float p = 0.f;
            if (v) {
                float e = a_s[col] + ad;
                e = e > 0.f ? e : NEG_SLOPE * e;
                p = __expf(e - m);
            }
            lpw[lane] = p;
            lcw[lane] = col;
            float s = p;
#pragma unroll
            for (int off = 1; off < 64; off <<= 1) s += __shfl_xor(s, off);
            den += s;
            int csz = end - c; if (csz > 64) csz = 64;
            int cnt = (csz + 1) & ~1;
            for (int j = 0; j < cnt; j += 2) {
                int jj = j + hh;
                float p_ = lpw[jj];
                int cc = lcw[jj];
                acc += p_ * h[(size_t)cc * 32 + l31];
            }
        }
    }
    acc += __shfl_xor(acc, 32);
    float vout = acc / (den + 1e-16f);
    vout += b[l31];
    vout = (vout - rm[l31]) * rsqrtf(rv[l31] + BN_EPS) * g[l31] + beta[l31];
    vout = vout > 0.f ? vout : (__expf(vout) - 1.f);
    if (lane < 32) obuf[(size_t)n * 32 + lane] = vout;
}

// layer3: 1 head, C=40. 1 wave/node; fused bias + log_softmax.
__global__ __launch_bounds__(256) void k_agg3(const float* __restrict__ h,
                                              const float* __restrict__ a_s,
                                              const float* __restrict__ a_d,
                                              const int* __restrict__ row_ptr,
                                              const int* __restrict__ col_idx,
                                              const float* __restrict__ b,
                                              float* __restrict__ out) {
    __shared__ float lp[4 * 64];
    __shared__ int   lc[4 * 64];
    const int wid  = threadIdx.x >> 6;
    const int lane = threadIdx.x & 63;
    const int n = (blockIdx.x << 2) + wid;
    if (n >= N_NODES) return;
    float* lpw = lp + (wid << 6);
    int*   lcw = lc + (wid << 6);
    const float ad = a_d[n];
    const int beg = row_ptr[n], end = row_ptr[n + 1];
    const int deg = end - beg;
    float den = 0.f, acc = 0.f;

    if (deg <= 64) {
        const int idx = beg + lane;
        const bool v = idx < end;
        const int col = v ? col_idx[idx] : 0;
        float e = NINF;
        if (v) {
            e = a_s[col] + ad;
            e = e > 0.f ? e : NEG_SLOPE * e;
        }
        float m = e;
#pragma unroll
        for (int off = 1; off < 64; off <<= 1) m = fmaxf(m, __shfl_xor(m, off));
        float p = __expf(e - m);
        lpw[lane] = p;
        lcw[lane] = col;
        den = p;
#pragma unroll
        for (int off = 1; off < 64; off <<= 1) den += __shfl_xor(den, off);
        const int cnt = (deg + 1) & ~1;
        for (int j = 0; j < cnt; j += 2) {
            float p0 = lpw[j], p1 = lpw[j + 1];
            int c0 = lcw[j], c1 = lcw[j + 1];
            if (lane < 40) {
                acc += p0 * h[(size_t)c0 * 40 + lane] + p1 * h[(size_t)c1 * 40 + lane];
            }
        }
    } else {
        float m = NINF;
        for (int c = beg; c < end; c += 64) {
            int idx = c + lane;
            if (idx < end) {
                float e = a_s[col_idx[idx]] + ad;
                e = e > 0.f ? e : NEG_SLOPE * e;
                m = fmaxf(m, e);
            }
        }
#pragma unroll
        for (int off = 1; off < 64; off <<= 1) m = fmaxf(m, __shfl_xor(m, off));
        for (int c = beg; c < end; c += 64) {
            int idx = c + lane;
            bool v = idx < end;
            int col = v ? col_idx[idx] : 0;
            float p = 0.f;
            if (v) {
                float e = a_s[col] + ad;
                e = e > 0.f ? e : NEG_SLOPE * e;
                p = __expf(e - m);
            }
            lpw[lane] = p;
            lcw[lane] = col;
            float s = p;
#pragma unroll
            for (int off = 1; off < 64; off <<= 1) s += __shfl_xor(s, off);
            den += s;
            int csz = end - c; if (csz > 64) csz = 64;
            int cnt = (csz + 1) & ~1;
            for (int j = 0; j < cnt; j += 2) {
                float p0 = lpw[j], p1 = lpw[j + 1];
                int c0i = lcw[j], c1i = lcw[j + 1];
                if (lane < 40) {
                    acc += p0 * h[(size_t)c0i * 40 + lane] + p1 * h[(size_t)c1i * 40 + lane];
                }
            }
        }
    }
    float vv = acc / (den + 1e-16f) + b[lane < 40 ? lane : 0];
    float vm = (lane < 40) ? vv : NINF;
#pragma unroll
    for (int off = 1; off < 64; off <<= 1) vm = fmaxf(vm, __shfl_xor(vm, off));
    float ex = (lane < 40) ? __expf(vv - vm) : 0.f;
#pragma unroll
    for (int off = 1; off < 64; off <<= 1) ex += __shfl_xor(ex, off);
    float res = vv - vm - logf(ex);
    if (lane < 40) out[(size_t)n * 40 + lane] = res;
}

// ---------------------------------------------------------------- launch

extern "C" void kernel_launch(void* const* d_in, const int* in_sizes, int n_in,
                              void* d_out, int out_size, void* d_ws, size_t ws_size,
                              hipStream_t stream) {
    const float* x    = (const float*)d_in[0];
    const int*   ei   = (const int*)d_in[1];
    const float* W1   = (const float*)d_in[2];
    const float* as1  = (const float*)d_in[3];
    const float* ad1  = (const float*)d_in[4];
    const float* b1   = (const float*)d_in[5];
    const float* g1   = (const float*)d_in[6];
    const float* be1  = (const float*)d_in[7];
    const float* rm1  = (const float*)d_in[8];
    const float* rv1  = (const float*)d_in[9];
    const float* W2   = (const float*)d_in[10];
    const float* as2  = (const float*)d_in[11];
    const float* ad2  = (const float*)d_in[12];
    const float* b2   = (const float*)d_in[13];
    const float* g2   = (const float*)d_in[14];
    const float* be2  = (const float*)d_in[15];
    const float* rm2  = (const float*)d_in[16];
    const float* rv2  = (const float*)d_in[17];
    const float* W3   = (const float*)d_in[18];
    const float* as3  = (const float*)d_in[19];
    const float* ad3  = (const float*)d_in[20];
    const float* b3   = (const float*)d_in[21];
    float* out = (float*)d_out;

    char* base = (char*)d_ws;
    size_t off = 0;
    auto carve = [&](size_t bytes) {
        char* p = base + off;
        off = (off + bytes + 255) & ~(size_t)255;
        return p;
    };
    int*   row_ptr = (int*)carve((N_NODES + 1) * sizeof(int));
    int*   cnt     = (int*)carve(N_NODES * sizeof(int));
    int*   cursor  = (int*)carve(N_NODES * sizeof(int));
    int*   sums    = (int*)carve(1024 * sizeof(int));
    int*   col_idx = (int*)carve((size_t)E_TOT * sizeof(int));
    float* a_s     = (float*)carve((size_t)N_NODES * 4 * sizeof(float));
    float* a_d     = (float*)carve((size_t)N_NODES * 4 * sizeof(float));
    float* hbuf    = (float*)carve((size_t)N_NODES * 128 * sizeof(float));
    float* obuf    = (float*)carve((size_t)N_NODES * 128 * sizeof(float));
    (void)ws_size;

    hipMemsetAsync(cnt, 0, N_NODES * sizeof(int), stream);
    {
        int g1b = (E_TOT + 255) / 256;
        k_count<<<g1b, 256, 0, stream>>>(ei, cnt);
        int nb = (N_NODES + 1023) / 1024;
        k_scan1<<<nb, 256, 0, stream>>>(cnt, row_ptr, sums);
        k_scan2<<<1, 1, 0, stream>>>(sums, nb);
        k_scan3<<<(N_NODES + 255) / 256, 256, 0, stream>>>(row_ptr, cursor, sums);
        k_scatter<<<g1b, 256, 0, stream>>>(ei, cursor, col_idx);
    }

    const int GEMM_GRID = (N_NODES + 63) / 64;
    const int WPN   = (N_NODES + 3) / 4;
    const int WP2N  = (N_NODES / 2 + 3) / 4;

    k_gemm<128, 128, 64, 256><<<GEMM_GRID, 256, 0, stream>>>(x, W1, hbuf, N_NODES);
    k_attproj1<<<WPN, 256, 0, stream>>>(hbuf, as1, ad1, a_s, a_d);
    k_agg1<<<WPN, 256, 0, stream>>>(hbuf, a_s, a_d, row_ptr, col_idx,
                                    b1, g1, be1, rm1, rv1, obuf);

    k_gemm<128, 32, 64, 256><<<GEMM_GRID, 256, 0, stream>>>(obuf, W2, hbuf, N_NODES);
    k_attproj2<<<WP2N, 256, 0, stream>>>(hbuf, as2, ad2, a_s, a_d);
    k_agg2<<<WPN, 256, 0, stream>>>(hbuf, a_s, a_d, row_ptr, col_idx,
                                    b2, g2, be2, rm2, rv2, obuf);

    k_gemm<32, 40, 64, 320><<<GEMM_GRID, 320, 0, stream>>>(obuf, W3, hbuf, N_NODES);
    k_attproj3<<<WPN, 256, 0, stream>>>(hbuf, as3, ad3, a_s, a_d);
    k_agg3<<<WPN, 256, 0, stream>>>(hbuf, a_s, a_d, row_ptr, col_idx, b3, out);
}

// Round 10
// 714.766 us; speedup vs baseline: 1.3538x; 1.0987x over previous
//
#include <hip/hip_runtime.h>
#include <math.h>

#define N_NODES 100000
#define N_EDGES 1600000
#define E_TOT   (N_EDGES + N_NODES)
#define BN_EPS  1e-5f
#define NEG_SLOPE 0.2f
#define NINF (-INFINITY)

// ---------------------------------------------------------------- CSR build

__global__ __launch_bounds__(256) void k_count(const int* __restrict__ ei,
                                               int* __restrict__ cnt) {
    int i = blockIdx.x * blockDim.x + threadIdx.x;
    if (i >= E_TOT) return;
    int d = (i < N_EDGES) ? ei[N_EDGES + i] : (i - N_EDGES);
    atomicAdd(&cnt[d], 1);
}

__global__ __launch_bounds__(256) void k_scan1(const int* __restrict__ cnt,
                                               int* __restrict__ excl,
                                               int* __restrict__ sums) {
    __shared__ int lds[256];
    int t = threadIdx.x;
    int base = blockIdx.x * 1024 + t * 4;
    int a[4];
#pragma unroll
    for (int j = 0; j < 4; ++j) a[j] = (base + j < N_NODES) ? cnt[base + j] : 0;
    int tot = a[0] + a[1] + a[2] + a[3];
    lds[t] = tot;
    __syncthreads();
    for (int off = 1; off < 256; off <<= 1) {
        int v = (t >= off) ? lds[t - off] : 0;
        __syncthreads();
        lds[t] += v;
        __syncthreads();
    }
    int run = lds[t] - tot;
#pragma unroll
    for (int j = 0; j < 4; ++j) {
        if (base + j < N_NODES) excl[base + j] = run;
        run += a[j];
    }
    if (t == 255) sums[blockIdx.x] = lds[255];
}

__global__ void k_scan2(int* sums, int nb) {
    if (blockIdx.x == 0 && threadIdx.x == 0) {
        int run = 0;
        for (int i = 0; i < nb; ++i) { int v = sums[i]; sums[i] = run; run += v; }
    }
}

__global__ __launch_bounds__(256) void k_scan3(int* __restrict__ row_ptr,
                                               int* __restrict__ cursor,
                                               const int* __restrict__ sums) {
    int i = blockIdx.x * blockDim.x + threadIdx.x;
    if (i == 0) row_ptr[N_NODES] = E_TOT;
    if (i >= N_NODES) return;
    int v = row_ptr[i] + sums[i >> 10];
    row_ptr[i] = v;
    cursor[i] = v;
}

__global__ __launch_bounds__(256) void k_scatter(const int* __restrict__ ei,
                                                 int* __restrict__ cursor,
                                                 int* __restrict__ col_idx) {
    int i = blockIdx.x * blockDim.x + threadIdx.x;
    if (i >= E_TOT) return;
    int s, d;
    if (i < N_EDGES) { s = ei[i]; d = ei[N_EDGES + i]; }
    else             { s = d = i - N_EDGES; }
    int pos = atomicAdd(&cursor[d], 1);
    col_idx[pos] = s;
}

// ---------------------------------------------------------------- GEMM (plain)

template <int K, int NC, int BM, int BLOCK>
__global__ __launch_bounds__(BLOCK) void k_gemm(const float* __restrict__ X,
                                                const float* __restrict__ W,
                                                float* __restrict__ Hout,
                                                int nrows) {
    constexpr int CG  = NC / 4;
    constexpr int TR  = BLOCK / CG;
    constexpr int RPT = BM / TR;
    constexpr int LDK = K + 4;
    __shared__ float xs[BM * LDK];
    const int row0 = blockIdx.x * BM;
    const int vr = (nrows - row0 < BM) ? (nrows - row0) : BM;
    const int nvalid = vr * K;
    for (int i = threadIdx.x * 4; i < BM * K; i += BLOCK * 4) {
        float4 v = make_float4(0.f, 0.f, 0.f, 0.f);
        if (i < nvalid) v = *(const float4*)(X + (size_t)row0 * K + i);
        int row = i / K, col = i % K;
        *(float4*)(&xs[row * LDK + col]) = v;
    }
    __syncthreads();
    const int tx = threadIdx.x % CG;
    const int ty = threadIdx.x / CG;
    float4 acc[RPT];
#pragma unroll
    for (int r = 0; r < RPT; ++r) acc[r] = make_float4(0.f, 0.f, 0.f, 0.f);
    for (int k4 = 0; k4 < K / 4; ++k4) {
        const float4 w0 = *(const float4*)(W + (k4 * 4 + 0) * NC + tx * 4);
        const float4 w1 = *(const float4*)(W + (k4 * 4 + 1) * NC + tx * 4);
        const float4 w2 = *(const float4*)(W + (k4 * 4 + 2) * NC + tx * 4);
        const float4 w3 = *(const float4*)(W + (k4 * 4 + 3) * NC + tx * 4);
#pragma unroll
        for (int r = 0; r < RPT; ++r) {
            const float4 xv = *(const float4*)(&xs[(ty * RPT + r) * LDK + k4 * 4]);
            acc[r].x = fmaf(xv.w, w3.x, fmaf(xv.z, w2.x, fmaf(xv.y, w1.x, fmaf(xv.x, w0.x, acc[r].x))));
            acc[r].y = fmaf(xv.w, w3.y, fmaf(xv.z, w2.y, fmaf(xv.y, w1.y, fmaf(xv.x, w0.y, acc[r].y))));
            acc[r].z = fmaf(xv.w, w3.z, fmaf(xv.z, w2.z, fmaf(xv.y, w1.z, fmaf(xv.x, w0.z, acc[r].z))));
            acc[r].w = fmaf(xv.w, w3.w, fmaf(xv.z, w2.w, fmaf(xv.y, w1.w, fmaf(xv.x, w0.w, acc[r].w))));
        }
    }
#pragma unroll
    for (int r = 0; r < RPT; ++r) {
        int row = row0 + ty * RPT + r;
        if (row < nrows) *(float4*)(Hout + (size_t)row * NC + tx * 4) = acc[r];
    }
}

// ------------------------------------------------ GEMM + fused attention proj
// Requires NC/HEADS_/4 == 8 (aligned 8-lane shuffle groups). Writes
// a_s[row*HEADS_+head], a_d likewise, from the accumulators — no hbuf re-read.

template <int K, int NC, int BM, int BLOCK, int HEADS_>
__global__ __launch_bounds__(BLOCK) void k_gemm_ap(const float* __restrict__ X,
                                                   const float* __restrict__ W,
                                                   const float* __restrict__ asf,
                                                   const float* __restrict__ adf,
                                                   float* __restrict__ a_s,
                                                   float* __restrict__ a_d,
                                                   float* __restrict__ Hout,
                                                   int nrows) {
    constexpr int CG  = NC / 4;
    constexpr int TR  = BLOCK / CG;
    constexpr int RPT = BM / TR;
    constexpr int LDK = K + 4;
    constexpr int GL  = NC / HEADS_ / 4;  // lanes per head group
    static_assert(GL == 8, "epilogue assumes 8-lane groups");
    __shared__ float xs[BM * LDK];
    const int row0 = blockIdx.x * BM;
    const int vr = (nrows - row0 < BM) ? (nrows - row0) : BM;
    const int nvalid = vr * K;
    for (int i = threadIdx.x * 4; i < BM * K; i += BLOCK * 4) {
        float4 v = make_float4(0.f, 0.f, 0.f, 0.f);
        if (i < nvalid) v = *(const float4*)(X + (size_t)row0 * K + i);
        int row = i / K, col = i % K;
        *(float4*)(&xs[row * LDK + col]) = v;
    }
    __syncthreads();
    const int tx = threadIdx.x % CG;
    const int ty = threadIdx.x / CG;
    float4 acc[RPT];
#pragma unroll
    for (int r = 0; r < RPT; ++r) acc[r] = make_float4(0.f, 0.f, 0.f, 0.f);
    for (int k4 = 0; k4 < K / 4; ++k4) {
        const float4 w0 = *(const float4*)(W + (k4 * 4 + 0) * NC + tx * 4);
        const float4 w1 = *(const float4*)(W + (k4 * 4 + 1) * NC + tx * 4);
        const float4 w2 = *(const float4*)(W + (k4 * 4 + 2) * NC + tx * 4);
        const float4 w3 = *(const float4*)(W + (k4 * 4 + 3) * NC + tx * 4);
#pragma unroll
        for (int r = 0; r < RPT; ++r) {
            const float4 xv = *(const float4*)(&xs[(ty * RPT + r) * LDK + k4 * 4]);
            acc[r].x = fmaf(xv.w, w3.x, fmaf(xv.z, w2.x, fmaf(xv.y, w1.x, fmaf(xv.x, w0.x, acc[r].x))));
            acc[r].y = fmaf(xv.w, w3.y, fmaf(xv.z, w2.y, fmaf(xv.y, w1.y, fmaf(xv.x, w0.y, acc[r].y))));
            acc[r].z = fmaf(xv.w, w3.z, fmaf(xv.z, w2.z, fmaf(xv.y, w1.z, fmaf(xv.x, w0.z, acc[r].z))));
            acc[r].w = fmaf(xv.w, w3.w, fmaf(xv.z, w2.w, fmaf(xv.y, w1.w, fmaf(xv.x, w0.w, acc[r].w))));
        }
    }
    const int head = tx >> 3;
    const float4 asv = *(const float4*)(asf + tx * 4);
    const float4 adv = *(const float4*)(adf + tx * 4);
#pragma unroll
    for (int r = 0; r < RPT; ++r) {
        int row = row0 + ty * RPT + r;
        float ps = acc[r].x * asv.x + acc[r].y * asv.y + acc[r].z * asv.z + acc[r].w * asv.w;
        float pd = acc[r].x * adv.x + acc[r].y * adv.y + acc[r].z * adv.z + acc[r].w * adv.w;
#pragma unroll
        for (int off = 1; off < GL; off <<= 1) {
            ps += __shfl_xor(ps, off);
            pd += __shfl_xor(pd, off);
        }
        if (row < nrows) {
            *(float4*)(Hout + (size_t)row * NC + tx * 4) = acc[r];
            if ((tx & (GL - 1)) == 0) {
                a_s[(size_t)row * HEADS_ + head] = ps;
                a_d[(size_t)row * HEADS_ + head] = pd;
            }
        }
    }
}

// ---------------------------------------------------------------- attproj3
// (NC=40 -> 10-lane groups don't align to shuffles; keep the separate kernel)

__global__ __launch_bounds__(256) void k_attproj3(const float* __restrict__ h,
                                                  const float* __restrict__ asf,
                                                  const float* __restrict__ adf,
                                                  float* __restrict__ a_s,
                                                  float* __restrict__ a_d) {
    int wv = (blockIdx.x * blockDim.x + threadIdx.x) >> 6;
    int lane = threadIdx.x & 63;
    if (wv >= N_NODES) return;
    float hv = (lane < 40) ? h[(size_t)wv * 40 + lane] : 0.f;
    float s = (lane < 40) ? hv * asf[lane] : 0.f;
    float d = (lane < 40) ? hv * adf[lane] : 0.f;
#pragma unroll
    for (int off = 1; off < 64; off <<= 1) { s += __shfl_xor(s, off); d += __shfl_xor(d, off); }
    if (lane == 0) { a_s[wv] = s; a_d[wv] = d; }
}

// ---------------------------------------------------------------- aggregation
// Two-phase per node; phase-2 gather unrolled 4 edges/iter (8 outstanding
// loads/wave in agg1) to raise MLP — the R5 profile showed latency-bound
// gather (VALUBusy 46%, HBM 47%, occupancy 79%).

// layer1: H=4, C=32 (128 feats). 1 wave/node; lane owns feats lane, lane+64.
__global__ __launch_bounds__(256) void k_agg1(const float* __restrict__ h,
                                              const float* __restrict__ a_s,
                                              const float* __restrict__ a_d,
                                              const int* __restrict__ row_ptr,
                                              const int* __restrict__ col_idx,
                                              const float* __restrict__ b,
                                              const float* __restrict__ g,
                                              const float* __restrict__ beta,
                                              const float* __restrict__ rm,
                                              const float* __restrict__ rv,
                                              float* __restrict__ obuf) {
    __shared__ float4 lp[4 * 64];
    __shared__ int    lc[4 * 64];
    const int wid  = threadIdx.x >> 6;
    const int lane = threadIdx.x & 63;
    const int n = (blockIdx.x << 2) + wid;
    if (n >= N_NODES) return;
    float4* lpw = lp + (wid << 6);
    int*    lcw = lc + (wid << 6);
    const int hi = lane >> 5;
    const float4 ad4 = *(const float4*)(a_d + (size_t)n * 4);
    const int beg = row_ptr[n], end = row_ptr[n + 1];
    const int deg = end - beg;
    float den0 = 0.f, den1 = 0.f, den2 = 0.f, den3 = 0.f;
    float acc0 = 0.f, acc1 = 0.f;

    if (deg <= 64) {
        const int idx = beg + lane;
        const bool v = idx < end;
        const int col = v ? col_idx[idx] : 0;
        float e0, e1, e2, e3;
        if (v) {
            float4 as4 = *(const float4*)(a_s + (size_t)col * 4);
            e0 = as4.x + ad4.x; e0 = e0 > 0.f ? e0 : NEG_SLOPE * e0;
            e1 = as4.y + ad4.y; e1 = e1 > 0.f ? e1 : NEG_SLOPE * e1;
            e2 = as4.z + ad4.z; e2 = e2 > 0.f ? e2 : NEG_SLOPE * e2;
            e3 = as4.w + ad4.w; e3 = e3 > 0.f ? e3 : NEG_SLOPE * e3;
        } else { e0 = e1 = e2 = e3 = NINF; }
        float m0 = e0, m1 = e1, m2 = e2, m3 = e3;
#pragma unroll
        for (int off = 1; off < 64; off <<= 1) {
            m0 = fmaxf(m0, __shfl_xor(m0, off));
            m1 = fmaxf(m1, __shfl_xor(m1, off));
            m2 = fmaxf(m2, __shfl_xor(m2, off));
            m3 = fmaxf(m3, __shfl_xor(m3, off));
        }
        float p0 = __expf(e0 - m0), p1 = __expf(e1 - m1);
        float p2 = __expf(e2 - m2), p3 = __expf(e3 - m3);
        lpw[lane] = make_float4(p0, p1, p2, p3);
        lcw[lane] = col;
        den0 = p0; den1 = p1; den2 = p2; den3 = p3;
#pragma unroll
        for (int off = 1; off < 64; off <<= 1) {
            den0 += __shfl_xor(den0, off); den1 += __shfl_xor(den1, off);
            den2 += __shfl_xor(den2, off); den3 += __shfl_xor(den3, off);
        }
        const int cnt = (deg + 3) & ~3;
        for (int j = 0; j < cnt; j += 4) {
            float4 pa = lpw[j],     pb = lpw[j + 1];
            float4 pc = lpw[j + 2], pq = lpw[j + 3];
            int c0 = lcw[j], c1 = lcw[j + 1], c2 = lcw[j + 2], c3 = lcw[j + 3];
            const float* r0 = h + (size_t)c0 * 128;
            const float* r1 = h + (size_t)c1 * 128;
            const float* r2 = h + (size_t)c2 * 128;
            const float* r3 = h + (size_t)c3 * 128;
            float h00 = r0[lane], h01 = r0[64 + lane];
            float h10 = r1[lane], h11 = r1[64 + lane];
            float h20 = r2[lane], h21 = r2[64 + lane];
            float h30 = r3[lane], h31 = r3[64 + lane];
            float pA0 = hi ? pa.y : pa.x, pB0 = hi ? pa.w : pa.z;
            float pA1 = hi ? pb.y : pb.x, pB1 = hi ? pb.w : pb.z;
            float pA2 = hi ? pc.y : pc.x, pB2 = hi ? pc.w : pc.z;
            float pA3 = hi ? pq.y : pq.x, pB3 = hi ? pq.w : pq.z;
            acc0 += pA0 * h00 + pA1 * h10 + pA2 * h20 + pA3 * h30;
            acc1 += pB0 * h01 + pB1 * h11 + pB2 * h21 + pB3 * h31;
        }
    } else {
        // slow path: chunked two-pass (deg > 64 is astronomically rare)
        float m0 = NINF, m1 = NINF, m2 = NINF, m3 = NINF;
        for (int c = beg; c < end; c += 64) {
            int idx = c + lane;
            bool v = idx < end;
            if (v) {
                int col = col_idx[idx];
                float4 as4 = *(const float4*)(a_s + (size_t)col * 4);
                float e0 = as4.x + ad4.x; e0 = e0 > 0.f ? e0 : NEG_SLOPE * e0;
                float e1 = as4.y + ad4.y; e1 = e1 > 0.f ? e1 : NEG_SLOPE * e1;
                float e2 = as4.z + ad4.z; e2 = e2 > 0.f ? e2 : NEG_SLOPE * e2;
                float e3 = as4.w + ad4.w; e3 = e3 > 0.f ? e3 : NEG_SLOPE * e3;
                m0 = fmaxf(m0, e0); m1 = fmaxf(m1, e1);
                m2 = fmaxf(m2, e2); m3 = fmaxf(m3, e3);
            }
        }
#pragma unroll
        for (int off = 1; off < 64; off <<= 1) {
            m0 = fmaxf(m0, __shfl_xor(m0, off));
            m1 = fmaxf(m1, __shfl_xor(m1, off));
            m2 = fmaxf(m2, __shfl_xor(m2, off));
            m3 = fmaxf(m3, __shfl_xor(m3, off));
        }
        for (int c = beg; c < end; c += 64) {
            int idx = c + lane;
            bool v = idx < end;
            int col = v ? col_idx[idx] : 0;
            float p0 = 0.f, p1 = 0.f, p2 = 0.f, p3 = 0.f;
            if (v) {
                float4 as4 = *(const float4*)(a_s + (size_t)col * 4);
                float e0 = as4.x + ad4.x; e0 = e0 > 0.f ? e0 : NEG_SLOPE * e0;
                float e1 = as4.y + ad4.y; e1 = e1 > 0.f ? e1 : NEG_SLOPE * e1;
                float e2 = as4.z + ad4.z; e2 = e2 > 0.f ? e2 : NEG_SLOPE * e2;
                float e3 = as4.w + ad4.w; e3 = e3 > 0.f ? e3 : NEG_SLOPE * e3;
                p0 = __expf(e0 - m0); p1 = __expf(e1 - m1);
                p2 = __expf(e2 - m2); p3 = __expf(e3 - m3);
            }
            lpw[lane] = make_float4(p0, p1, p2, p3);
            lcw[lane] = col;
            float s0 = p0, s1 = p1, s2 = p2, s3 = p3;
#pragma unroll
            for (int off = 1; off < 64; off <<= 1) {
                s0 += __shfl_xor(s0, off); s1 += __shfl_xor(s1, off);
                s2 += __shfl_xor(s2, off); s3 += __shfl_xor(s3, off);
            }
            den0 += s0; den1 += s1; den2 += s2; den3 += s3;
            int csz = end - c; if (csz > 64) csz = 64;
            int cnt = (csz + 3) & ~3;
            for (int j = 0; j < cnt; j += 4) {
                float4 pa = lpw[j],     pb = lpw[j + 1];
                float4 pc = lpw[j + 2], pq = lpw[j + 3];
                int c0i = lcw[j], c1i = lcw[j + 1], c2i = lcw[j + 2], c3i = lcw[j + 3];
                const float* r0 = h + (size_t)c0i * 128;
                const float* r1 = h + (size_t)c1i * 128;
                const float* r2 = h + (size_t)c2i * 128;
                const float* r3 = h + (size_t)c3i * 128;
                float h00 = r0[lane], h01 = r0[64 + lane];
                float h10 = r1[lane], h11 = r1[64 + lane];
                float h20 = r2[lane], h21 = r2[64 + lane];
                float h30 = r3[lane], h31 = r3[64 + lane];
                float pA0 = hi ? pa.y : pa.x, pB0 = hi ? pa.w : pa.z;
                float pA1 = hi ? pb.y : pb.x, pB1 = hi ? pb.w : pb.z;
                float pA2 = hi ? pc.y : pc.x, pB2 = hi ? pc.w : pc.z;
                float pA3 = hi ? pq.y : pq.x, pB3 = hi ? pq.w : pq.z;
                acc0 += pA0 * h00 + pA1 * h10 + pA2 * h20 + pA3 * h30;
                acc1 += pB0 * h01 + pB1 * h11 + pB2 * h21 + pB3 * h31;
            }
        }
    }

    float inv0 = 1.f / (den0 + 1e-16f), inv1 = 1.f / (den1 + 1e-16f);
    float inv2 = 1.f / (den2 + 1e-16f), inv3 = 1.f / (den3 + 1e-16f);
    float f0 = acc0 * (hi ? inv1 : inv0);
    float f1 = acc1 * (hi ? inv3 : inv2);
    int fA = lane, fB = lane + 64;
    f0 += b[fA]; f1 += b[fB];
    f0 = (f0 - rm[fA]) * rsqrtf(rv[fA] + BN_EPS) * g[fA] + beta[fA];
    f1 = (f1 - rm[fB]) * rsqrtf(rv[fB] + BN_EPS) * g[fB] + beta[fB];
    f0 = f0 > 0.f ? f0 : (__expf(f0) - 1.f);
    f1 = f1 > 0.f ? f1 : (__expf(f1) - 1.f);
    obuf[(size_t)n * 128 + fA] = f0;
    obuf[(size_t)n * 128 + fB] = f1;
}

// layer2: 1 head, C=32. 1 wave/node; gather does 8 edges/iter (4 per half),
// folded by shfl_xor(acc,32) at the end.
__global__ __launch_bounds__(256) void k_agg2(const float* __restrict__ h,
                                              const float* __restrict__ a_s,
                                              const float* __restrict__ a_d,
                                              const int* __restrict__ row_ptr,
                                              const int* __restrict__ col_idx,
                                              const float* __restrict__ b,
                                              const float* __restrict__ g,
                                              const float* __restrict__ beta,
                                              const float* __restrict__ rm,
                                              const float* __restrict__ rv,
                                              float* __restrict__ obuf) {
    __shared__ float lp[4 * 64];
    __shared__ int   lc[4 * 64];
    const int wid  = threadIdx.x >> 6;
    const int lane = threadIdx.x & 63;
    const int n = (blockIdx.x << 2) + wid;
    if (n >= N_NODES) return;
    float* lpw = lp + (wid << 6);
    int*   lcw = lc + (wid << 6);
    const int l31 = lane & 31, hh = lane >> 5;
    const float ad = a_d[n];
    const int beg = row_ptr[n], end = row_ptr[n + 1];
    const int deg = end - beg;
    float den = 0.f, acc = 0.f;

    if (deg <= 64) {
        const int idx = beg + lane;
        const bool v = idx < end;
        const int col = v ? col_idx[idx] : 0;
        float e = NINF;
        if (v) {
            e = a_s[col] + ad;
            e = e > 0.f ? e : NEG_SLOPE * e;
        }
        float m = e;
#pragma unroll
        for (int off = 1; off < 64; off <<= 1) m = fmaxf(m, __shfl_xor(m, off));
        float p = __expf(e - m);
        lpw[lane] = p;
        lcw[lane] = col;
        den = p;
#pragma unroll
        for (int off = 1; off < 64; off <<= 1) den += __shfl_xor(den, off);
        const int cnt = (deg + 7) & ~7;
        for (int j = 0; j < cnt; j += 8) {
            int j0 = j + (hh << 2);
            float p0 = lpw[j0], p1 = lpw[j0 + 1], p2 = lpw[j0 + 2], p3 = lpw[j0 + 3];
            int c0 = lcw[j0], c1 = lcw[j0 + 1], c2 = lcw[j0 + 2], c3 = lcw[j0 + 3];
            acc += p0 * h[(size_t)c0 * 32 + l31] + p1 * h[(size_t)c1 * 32 + l31]
                 + p2 * h[(size_t)c2 * 32 + l31] + p3 * h[(size_t)c3 * 32 + l31];
        }
    } else {
        float m = NINF;
        for (int c = beg; c < end; c += 64) {
            int idx = c + lane;
            if (idx < end) {
                float e = a_s[col_idx[idx]] + ad;
                e = e > 0.f ? e : NEG_SLOPE * e;
                m = fmaxf(m, e);
            }
        }
#pragma unroll
        for (int off = 1; off < 64; off <<= 1) m = fmaxf(m, __shfl_xor(m, off));
        for (int c = beg; c < end; c += 64) {
            int idx = c + lane;
            bool v = idx < end;
            int col = v ? col_idx[idx] : 0;
            float p = 0.f;
            if (v) {
                float e = a_s[col] + ad;
                e = e > 0.f ? e : NEG_SLOPE * e;
                p = __expf(e - m);
            }
            lpw[lane] = p;
            lcw[lane] = col;
            float s = p;
#pragma unroll
            for (int off = 1; off < 64; off <<= 1) s += __shfl_xor(s, off);
            den += s;
            int csz = end - c; if (csz > 64) csz = 64;
            int cnt = (csz + 7) & ~7;
            for (int j = 0; j < cnt; j += 8) {
                int j0 = j + (hh << 2);
                float p0 = lpw[j0], p1 = lpw[j0 + 1], p2 = lpw[j0 + 2], p3 = lpw[j0 + 3];
                int c0 = lcw[j0], c1 = lcw[j0 + 1], c2 = lcw[j0 + 2], c3 = lcw[j0 + 3];
                acc += p0 * h[(size_t)c0 * 32 + l31] + p1 * h[(size_t)c1 * 32 + l31]
                     + p2 * h[(size_t)c2 * 32 + l31] + p3 * h[(size_t)c3 * 32 + l31];
            }
        }
    }
    acc += __shfl_xor(acc, 32);
    float vout = acc / (den + 1e-16f);
    vout += b[l31];
    vout = (vout - rm[l31]) * rsqrtf(rv[l31] + BN_EPS) * g[l31] + beta[l31];
    vout = vout > 0.f ? vout : (__expf(vout) - 1.f);
    if (lane < 32) obuf[(size_t)n * 32 + lane] = vout;
}

// layer3: 1 head, C=40. 1 wave/node; fused bias + log_softmax.
__global__ __launch_bounds__(256) void k_agg3(const float* __restrict__ h,
                                              const float* __restrict__ a_s,
                                              const float* __restrict__ a_d,
                                              const int* __restrict__ row_ptr,
                                              const int* __restrict__ col_idx,
                                              const float* __restrict__ b,
                                              float* __restrict__ out) {
    __shared__ float lp[4 * 64];
    __shared__ int   lc[4 * 64];
    const int wid  = threadIdx.x >> 6;
    const int lane = threadIdx.x & 63;
    const int n = (blockIdx.x << 2) + wid;
    if (n >= N_NODES) return;
    float* lpw = lp + (wid << 6);
    int*   lcw = lc + (wid << 6);
    const float ad = a_d[n];
    const int beg = row_ptr[n], end = row_ptr[n + 1];
    const int deg = end - beg;
    float den = 0.f, acc = 0.f;

    if (deg <= 64) {
        const int idx = beg + lane;
        const bool v = idx < end;
        const int col = v ? col_idx[idx] : 0;
        float e = NINF;
        if (v) {
            e = a_s[col] + ad;
            e = e > 0.f ? e : NEG_SLOPE * e;
        }
        float m = e;
#pragma unroll
        for (int off = 1; off < 64; off <<= 1) m = fmaxf(m, __shfl_xor(m, off));
        float p = __expf(e - m);
        lpw[lane] = p;
        lcw[lane] = col;
        den = p;
#pragma unroll
        for (int off = 1; off < 64; off <<= 1) den += __shfl_xor(den, off);
        const int cnt = (deg + 3) & ~3;
        for (int j = 0; j < cnt; j += 4) {
            float p0 = lpw[j], p1 = lpw[j + 1], p2 = lpw[j + 2], p3 = lpw[j + 3];
            int c0 = lcw[j], c1 = lcw[j + 1], c2 = lcw[j + 2], c3 = lcw[j + 3];
            if (lane < 40) {
                acc += p0 * h[(size_t)c0 * 40 + lane] + p1 * h[(size_t)c1 * 40 + lane]
                     + p2 * h[(size_t)c2 * 40 + lane] + p3 * h[(size_t)c3 * 40 + lane];
            }
        }
    } else {
        float m = NINF;
        for (int c = beg; c < end; c += 64) {
            int idx = c + lane;
            if (idx < end) {
                float e = a_s[col_idx[idx]] + ad;
                e = e > 0.f ? e : NEG_SLOPE * e;
                m = fmaxf(m, e);
            }
        }
#pragma unroll
        for (int off = 1; off < 64; off <<= 1) m = fmaxf(m, __shfl_xor(m, off));
        for (int c = beg; c < end; c += 64) {
            int idx = c + lane;
            bool v = idx < end;
            int col = v ? col_idx[idx] : 0;
            float p = 0.f;
            if (v) {
                float e = a_s[col] + ad;
                e = e > 0.f ? e : NEG_SLOPE * e;
                p = __expf(e - m);
            }
            lpw[lane] = p;
            lcw[lane] = col;
            float s = p;
#pragma unroll
            for (int off = 1; off < 64; off <<= 1) s += __shfl_xor(s, off);
            den += s;
            int csz = end - c; if (csz > 64) csz = 64;
            int cnt = (csz + 3) & ~3;
            for (int j = 0; j < cnt; j += 4) {
                float p0 = lpw[j], p1 = lpw[j + 1], p2 = lpw[j + 2], p3 = lpw[j + 3];
                int c0 = lcw[j], c1 = lcw[j + 1], c2 = lcw[j + 2], c3 = lcw[j + 3];
                if (lane < 40) {
                    acc += p0 * h[(size_t)c0 * 40 + lane] + p1 * h[(size_t)c1 * 40 + lane]
                         + p2 * h[(size_t)c2 * 40 + lane] + p3 * h[(size_t)c3 * 40 + lane];
                }
            }
        }
    }
    float vv = acc / (den + 1e-16f) + b[lane < 40 ? lane : 0];
    float vm = (lane < 40) ? vv : NINF;
#pragma unroll
    for (int off = 1; off < 64; off <<= 1) vm = fmaxf(vm, __shfl_xor(vm, off));
    float ex = (lane < 40) ? __expf(vv - vm) : 0.f;
#pragma unroll
    for (int off = 1; off < 64; off <<= 1) ex += __shfl_xor(ex, off);
    float res = vv - vm - logf(ex);
    if (lane < 40) out[(size_t)n * 40 + lane] = res;
}

// ---------------------------------------------------------------- launch

extern "C" void kernel_launch(void* const* d_in, const int* in_sizes, int n_in,
                              void* d_out, int out_size, void* d_ws, size_t ws_size,
                              hipStream_t stream) {
    const float* x    = (const float*)d_in[0];
    const int*   ei   = (const int*)d_in[1];
    const float* W1   = (const float*)d_in[2];
    const float* as1  = (const float*)d_in[3];
    const float* ad1  = (const float*)d_in[4];
    const float* b1   = (const float*)d_in[5];
    const float* g1   = (const float*)d_in[6];
    const float* be1  = (const float*)d_in[7];
    const float* rm1  = (const float*)d_in[8];
    const float* rv1  = (const float*)d_in[9];
    const float* W2   = (const float*)d_in[10];
    const float* as2  = (const float*)d_in[11];
    const float* ad2  = (const float*)d_in[12];
    const float* b2   = (const float*)d_in[13];
    const float* g2   = (const float*)d_in[14];
    const float* be2  = (const float*)d_in[15];
    const float* rm2  = (const float*)d_in[16];
    const float* rv2  = (const float*)d_in[17];
    const float* W3   = (const float*)d_in[18];
    const float* as3  = (const float*)d_in[19];
    const float* ad3  = (const float*)d_in[20];
    const float* b3   = (const float*)d_in[21];
    float* out = (float*)d_out;

    char* base = (char*)d_ws;
    size_t off = 0;
    auto carve = [&](size_t bytes) {
        char* p = base + off;
        off = (off + bytes + 255) & ~(size_t)255;
        return p;
    };
    int*   row_ptr = (int*)carve((N_NODES + 1) * sizeof(int));
    int*   cnt     = (int*)carve(N_NODES * sizeof(int));
    int*   cursor  = (int*)carve(N_NODES * sizeof(int));
    int*   sums    = (int*)carve(1024 * sizeof(int));
    int*   col_idx = (int*)carve((size_t)E_TOT * sizeof(int));
    float* a_s     = (float*)carve((size_t)N_NODES * 4 * sizeof(float));
    float* a_d     = (float*)carve((size_t)N_NODES * 4 * sizeof(float));
    float* hbuf    = (float*)carve((size_t)N_NODES * 128 * sizeof(float));
    float* obuf    = (float*)carve((size_t)N_NODES * 128 * sizeof(float));
    (void)ws_size;

    hipMemsetAsync(cnt, 0, N_NODES * sizeof(int), stream);
    {
        int g1b = (E_TOT + 255) / 256;
        k_count<<<g1b, 256, 0, stream>>>(ei, cnt);
        int nb = (N_NODES + 1023) / 1024;
        k_scan1<<<nb, 256, 0, stream>>>(cnt, row_ptr, sums);
        k_scan2<<<1, 1, 0, stream>>>(sums, nb);
        k_scan3<<<(N_NODES + 255) / 256, 256, 0, stream>>>(row_ptr, cursor, sums);
        k_scatter<<<g1b, 256, 0, stream>>>(ei, cursor, col_idx);
    }

    const int GEMM_GRID = (N_NODES + 63) / 64;
    const int WPN = (N_NODES + 3) / 4;

    // layer1: GEMM + fused attproj (4 heads)
    k_gemm_ap<128, 128, 64, 256, 4><<<GEMM_GRID, 256, 0, stream>>>(
        x, W1, as1, ad1, a_s, a_d, hbuf, N_NODES);
    k_agg1<<<WPN, 256, 0, stream>>>(hbuf, a_s, a_d, row_ptr, col_idx,
                                    b1, g1, be1, rm1, rv1, obuf);

    // layer2: GEMM + fused attproj (1 head)
    k_gemm_ap<128, 32, 64, 256, 1><<<GEMM_GRID, 256, 0, stream>>>(
        obuf, W2, as2, ad2, a_s, a_d, hbuf, N_NODES);
    k_agg2<<<WPN, 256, 0, stream>>>(hbuf, a_s, a_d, row_ptr, col_idx,
                                    b2, g2, be2, rm2, rv2, obuf);

    // layer3: plain GEMM (40 cols -> 10-lane groups, no clean shuffle fusion)
    k_gemm<32, 40, 64, 320><<<GEMM_GRID, 320, 0, stream>>>(obuf, W3, hbuf, N_NODES);
    k_attproj3<<<WPN, 256, 0, stream>>>(hbuf, as3, ad3, a_s, a_d);
    k_agg3<<<WPN, 256, 0, stream>>>(hbuf, a_s, a_d, row_ptr, col_idx, b3, out);
}

// Round 11
// 664.844 us; speedup vs baseline: 1.4554x; 1.0751x over previous
//
#include <hip/hip_runtime.h>
#include <math.h>

#define N_NODES 100000
#define N_EDGES 1600000
#define E_TOT   (N_EDGES + N_NODES)
#define BN_EPS  1e-5f
#define NEG_SLOPE 0.2f
#define NINF (-INFINITY)

// bf16 helpers (manual, RNE) — avoids header API variance
__device__ __forceinline__ unsigned short f2bf(float f) {
    unsigned int u = __float_as_uint(f);
    unsigned int r = (u + 0x7FFFu + ((u >> 16) & 1u)) >> 16;
    return (unsigned short)r;
}
__device__ __forceinline__ float bflo(unsigned int v) {  // low bf16 of packed pair
    return __uint_as_float(v << 16);
}
__device__ __forceinline__ float bfhi(unsigned int v) {  // high bf16 of packed pair
    return __uint_as_float(v & 0xFFFF0000u);
}
__device__ __forceinline__ float sel4(float a, float b, float c, float d, int i) {
    float lo = (i & 1) ? b : a;
    float hi = (i & 1) ? d : c;
    return (i & 2) ? hi : lo;
}

// ---------------------------------------------------------------- CSR build

__global__ __launch_bounds__(256) void k_count(const int* __restrict__ ei,
                                               int* __restrict__ cnt) {
    int i = blockIdx.x * blockDim.x + threadIdx.x;
    if (i >= E_TOT) return;
    int d = (i < N_EDGES) ? ei[N_EDGES + i] : (i - N_EDGES);
    atomicAdd(&cnt[d], 1);
}

__global__ __launch_bounds__(256) void k_scan1(const int* __restrict__ cnt,
                                               int* __restrict__ excl,
                                               int* __restrict__ sums) {
    __shared__ int lds[256];
    int t = threadIdx.x;
    int base = blockIdx.x * 1024 + t * 4;
    int a[4];
#pragma unroll
    for (int j = 0; j < 4; ++j) a[j] = (base + j < N_NODES) ? cnt[base + j] : 0;
    int tot = a[0] + a[1] + a[2] + a[3];
    lds[t] = tot;
    __syncthreads();
    for (int off = 1; off < 256; off <<= 1) {
        int v = (t >= off) ? lds[t - off] : 0;
        __syncthreads();
        lds[t] += v;
        __syncthreads();
    }
    int run = lds[t] - tot;
#pragma unroll
    for (int j = 0; j < 4; ++j) {
        if (base + j < N_NODES) excl[base + j] = run;
        run += a[j];
    }
    if (t == 255) sums[blockIdx.x] = lds[255];
}

__global__ void k_scan2(int* sums, int nb) {
    if (blockIdx.x == 0 && threadIdx.x == 0) {
        int run = 0;
        for (int i = 0; i < nb; ++i) { int v = sums[i]; sums[i] = run; run += v; }
    }
}

__global__ __launch_bounds__(256) void k_scan3(int* __restrict__ row_ptr,
                                               int* __restrict__ cursor,
                                               const int* __restrict__ sums) {
    int i = blockIdx.x * blockDim.x + threadIdx.x;
    if (i == 0) row_ptr[N_NODES] = E_TOT;
    if (i >= N_NODES) return;
    int v = row_ptr[i] + sums[i >> 10];
    row_ptr[i] = v;
    cursor[i] = v;
}

// nontemporal scattered store: avoid read-for-ownership/writeback amplification
__global__ __launch_bounds__(256) void k_scatter(const int* __restrict__ ei,
                                                 int* __restrict__ cursor,
                                                 int* __restrict__ col_idx) {
    int i = blockIdx.x * blockDim.x + threadIdx.x;
    if (i >= E_TOT) return;
    int s, d;
    if (i < N_EDGES) { s = ei[i]; d = ei[N_EDGES + i]; }
    else             { s = d = i - N_EDGES; }
    int pos = atomicAdd(&cursor[d], 1);
    __builtin_nontemporal_store(s, &col_idx[pos]);
}

// ---------------------------------------------------------------- GEMM (plain)

template <int K, int NC, int BM, int BLOCK>
__global__ __launch_bounds__(BLOCK) void k_gemm(const float* __restrict__ X,
                                                const float* __restrict__ W,
                                                float* __restrict__ Hout,
                                                int nrows) {
    constexpr int CG  = NC / 4;
    constexpr int TR  = BLOCK / CG;
    constexpr int RPT = BM / TR;
    constexpr int LDK = K + 4;
    __shared__ float xs[BM * LDK];
    const int row0 = blockIdx.x * BM;
    const int vr = (nrows - row0 < BM) ? (nrows - row0) : BM;
    const int nvalid = vr * K;
    for (int i = threadIdx.x * 4; i < BM * K; i += BLOCK * 4) {
        float4 v = make_float4(0.f, 0.f, 0.f, 0.f);
        if (i < nvalid) v = *(const float4*)(X + (size_t)row0 * K + i);
        int row = i / K, col = i % K;
        *(float4*)(&xs[row * LDK + col]) = v;
    }
    __syncthreads();
    const int tx = threadIdx.x % CG;
    const int ty = threadIdx.x / CG;
    float4 acc[RPT];
#pragma unroll
    for (int r = 0; r < RPT; ++r) acc[r] = make_float4(0.f, 0.f, 0.f, 0.f);
    for (int k4 = 0; k4 < K / 4; ++k4) {
        const float4 w0 = *(const float4*)(W + (k4 * 4 + 0) * NC + tx * 4);
        const float4 w1 = *(const float4*)(W + (k4 * 4 + 1) * NC + tx * 4);
        const float4 w2 = *(const float4*)(W + (k4 * 4 + 2) * NC + tx * 4);
        const float4 w3 = *(const float4*)(W + (k4 * 4 + 3) * NC + tx * 4);
#pragma unroll
        for (int r = 0; r < RPT; ++r) {
            const float4 xv = *(const float4*)(&xs[(ty * RPT + r) * LDK + k4 * 4]);
            acc[r].x = fmaf(xv.w, w3.x, fmaf(xv.z, w2.x, fmaf(xv.y, w1.x, fmaf(xv.x, w0.x, acc[r].x))));
            acc[r].y = fmaf(xv.w, w3.y, fmaf(xv.z, w2.y, fmaf(xv.y, w1.y, fmaf(xv.x, w0.y, acc[r].y))));
            acc[r].z = fmaf(xv.w, w3.z, fmaf(xv.z, w2.z, fmaf(xv.y, w1.z, fmaf(xv.x, w0.z, acc[r].z))));
            acc[r].w = fmaf(xv.w, w3.w, fmaf(xv.z, w2.w, fmaf(xv.y, w1.w, fmaf(xv.x, w0.w, acc[r].w))));
        }
    }
#pragma unroll
    for (int r = 0; r < RPT; ++r) {
        int row = row0 + ty * RPT + r;
        if (row < nrows) *(float4*)(Hout + (size_t)row * NC + tx * 4) = acc[r];
    }
}

// ------------------------------------------------ GEMM + fused attention proj
// a_s/a_d computed from FP32 accumulators (aligned 8-lane shuffle groups).
// BF16OUT: store Hout as packed bf16 (halves the downstream gather traffic).

template <int K, int NC, int BM, int BLOCK, int HEADS_, bool BF16OUT>
__global__ __launch_bounds__(BLOCK) void k_gemm_ap(const float* __restrict__ X,
                                                   const float* __restrict__ W,
                                                   const float* __restrict__ asf,
                                                   const float* __restrict__ adf,
                                                   float* __restrict__ a_s,
                                                   float* __restrict__ a_d,
                                                   void* __restrict__ Hout,
                                                   int nrows) {
    constexpr int CG  = NC / 4;
    constexpr int TR  = BLOCK / CG;
    constexpr int RPT = BM / TR;
    constexpr int LDK = K + 4;
    constexpr int GL  = NC / HEADS_ / 4;  // lanes per head group
    static_assert(GL == 8, "epilogue assumes 8-lane groups");
    __shared__ float xs[BM * LDK];
    const int row0 = blockIdx.x * BM;
    const int vr = (nrows - row0 < BM) ? (nrows - row0) : BM;
    const int nvalid = vr * K;
    for (int i = threadIdx.x * 4; i < BM * K; i += BLOCK * 4) {
        float4 v = make_float4(0.f, 0.f, 0.f, 0.f);
        if (i < nvalid) v = *(const float4*)(X + (size_t)row0 * K + i);
        int row = i / K, col = i % K;
        *(float4*)(&xs[row * LDK + col]) = v;
    }
    __syncthreads();
    const int tx = threadIdx.x % CG;
    const int ty = threadIdx.x / CG;
    float4 acc[RPT];
#pragma unroll
    for (int r = 0; r < RPT; ++r) acc[r] = make_float4(0.f, 0.f, 0.f, 0.f);
    for (int k4 = 0; k4 < K / 4; ++k4) {
        const float4 w0 = *(const float4*)(W + (k4 * 4 + 0) * NC + tx * 4);
        const float4 w1 = *(const float4*)(W + (k4 * 4 + 1) * NC + tx * 4);
        const float4 w2 = *(const float4*)(W + (k4 * 4 + 2) * NC + tx * 4);
        const float4 w3 = *(const float4*)(W + (k4 * 4 + 3) * NC + tx * 4);
#pragma unroll
        for (int r = 0; r < RPT; ++r) {
            const float4 xv = *(const float4*)(&xs[(ty * RPT + r) * LDK + k4 * 4]);
            acc[r].x = fmaf(xv.w, w3.x, fmaf(xv.z, w2.x, fmaf(xv.y, w1.x, fmaf(xv.x, w0.x, acc[r].x))));
            acc[r].y = fmaf(xv.w, w3.y, fmaf(xv.z, w2.y, fmaf(xv.y, w1.y, fmaf(xv.x, w0.y, acc[r].y))));
            acc[r].z = fmaf(xv.w, w3.z, fmaf(xv.z, w2.z, fmaf(xv.y, w1.z, fmaf(xv.x, w0.z, acc[r].z))));
            acc[r].w = fmaf(xv.w, w3.w, fmaf(xv.z, w2.w, fmaf(xv.y, w1.w, fmaf(xv.x, w0.w, acc[r].w))));
        }
    }
    const int head = tx >> 3;
    const float4 asv = *(const float4*)(asf + tx * 4);
    const float4 adv = *(const float4*)(adf + tx * 4);
#pragma unroll
    for (int r = 0; r < RPT; ++r) {
        int row = row0 + ty * RPT + r;
        float ps = acc[r].x * asv.x + acc[r].y * asv.y + acc[r].z * asv.z + acc[r].w * asv.w;
        float pd = acc[r].x * adv.x + acc[r].y * adv.y + acc[r].z * adv.z + acc[r].w * adv.w;
#pragma unroll
        for (int off = 1; off < GL; off <<= 1) {
            ps += __shfl_xor(ps, off);
            pd += __shfl_xor(pd, off);
        }
        if (row < nrows) {
            if constexpr (BF16OUT) {
                ushort4 o;
                o.x = f2bf(acc[r].x); o.y = f2bf(acc[r].y);
                o.z = f2bf(acc[r].z); o.w = f2bf(acc[r].w);
                *(ushort4*)((unsigned short*)Hout + (size_t)row * NC + tx * 4) = o;
            } else {
                *(float4*)((float*)Hout + (size_t)row * NC + tx * 4) = acc[r];
            }
            if ((tx & (GL - 1)) == 0) {
                a_s[(size_t)row * HEADS_ + head] = ps;
                a_d[(size_t)row * HEADS_ + head] = pd;
            }
        }
    }
}

// ---------------------------------------------------------------- attproj3

__global__ __launch_bounds__(256) void k_attproj3(const float* __restrict__ h,
                                                  const float* __restrict__ asf,
                                                  const float* __restrict__ adf,
                                                  float* __restrict__ a_s,
                                                  float* __restrict__ a_d) {
    int wv = (blockIdx.x * blockDim.x + threadIdx.x) >> 6;
    int lane = threadIdx.x & 63;
    if (wv >= N_NODES) return;
    float hv = (lane < 40) ? h[(size_t)wv * 40 + lane] : 0.f;
    float s = (lane < 40) ? hv * asf[lane] : 0.f;
    float d = (lane < 40) ? hv * adf[lane] : 0.f;
#pragma unroll
    for (int off = 1; off < 64; off <<= 1) { s += __shfl_xor(s, off); d += __shfl_xor(d, off); }
    if (lane == 0) { a_s[wv] = s; a_d[wv] = d; }
}

// ---------------------------------------------------------------- aggregation

// layer1: H=4, C=32 (128 feats), bf16 h. Lane owns feats {2*lane, 2*lane+1}
// (same head hd=lane>>4) -> full 256B row fetched with one 4B load per lane.
__global__ __launch_bounds__(256) void k_agg1(const unsigned short* __restrict__ hb,
                                              const float* __restrict__ a_s,
                                              const float* __restrict__ a_d,
                                              const int* __restrict__ row_ptr,
                                              const int* __restrict__ col_idx,
                                              const float* __restrict__ b,
                                              const float* __restrict__ g,
                                              const float* __restrict__ beta,
                                              const float* __restrict__ rm,
                                              const float* __restrict__ rv,
                                              float* __restrict__ obuf) {
    __shared__ float4 lp[4 * 64];
    __shared__ int    lc[4 * 64];
    const int wid  = threadIdx.x >> 6;
    const int lane = threadIdx.x & 63;
    const int n = (blockIdx.x << 2) + wid;
    if (n >= N_NODES) return;
    float4* lpw = lp + (wid << 6);
    int*    lcw = lc + (wid << 6);
    const int hd = lane >> 4;  // head of feats 2*lane, 2*lane+1
    const float4 ad4 = *(const float4*)(a_d + (size_t)n * 4);
    const int beg = row_ptr[n], end = row_ptr[n + 1];
    const int deg = end - beg;
    float den0 = 0.f, den1 = 0.f, den2 = 0.f, den3 = 0.f;
    float acc0 = 0.f, acc1 = 0.f;

    if (deg <= 64) {
        const int idx = beg + lane;
        const bool v = idx < end;
        const int col = v ? col_idx[idx] : 0;
        float e0, e1, e2, e3;
        if (v) {
            float4 as4 = *(const float4*)(a_s + (size_t)col * 4);
            e0 = as4.x + ad4.x; e0 = e0 > 0.f ? e0 : NEG_SLOPE * e0;
            e1 = as4.y + ad4.y; e1 = e1 > 0.f ? e1 : NEG_SLOPE * e1;
            e2 = as4.z + ad4.z; e2 = e2 > 0.f ? e2 : NEG_SLOPE * e2;
            e3 = as4.w + ad4.w; e3 = e3 > 0.f ? e3 : NEG_SLOPE * e3;
        } else { e0 = e1 = e2 = e3 = NINF; }
        float m0 = e0, m1 = e1, m2 = e2, m3 = e3;
#pragma unroll
        for (int off = 1; off < 64; off <<= 1) {
            m0 = fmaxf(m0, __shfl_xor(m0, off));
            m1 = fmaxf(m1, __shfl_xor(m1, off));
            m2 = fmaxf(m2, __shfl_xor(m2, off));
            m3 = fmaxf(m3, __shfl_xor(m3, off));
        }
        float p0 = __expf(e0 - m0), p1 = __expf(e1 - m1);
        float p2 = __expf(e2 - m2), p3 = __expf(e3 - m3);
        lpw[lane] = make_float4(p0, p1, p2, p3);
        lcw[lane] = col;
        den0 = p0; den1 = p1; den2 = p2; den3 = p3;
#pragma unroll
        for (int off = 1; off < 64; off <<= 1) {
            den0 += __shfl_xor(den0, off); den1 += __shfl_xor(den1, off);
            den2 += __shfl_xor(den2, off); den3 += __shfl_xor(den3, off);
        }
        const int cnt = (deg + 3) & ~3;
        for (int j = 0; j < cnt; j += 4) {
            float4 pa = lpw[j],     pb = lpw[j + 1];
            float4 pc = lpw[j + 2], pq = lpw[j + 3];
            int c0 = lcw[j], c1 = lcw[j + 1], c2 = lcw[j + 2], c3 = lcw[j + 3];
            unsigned int v0 = *(const unsigned int*)(hb + (size_t)c0 * 128 + 2 * lane);
            unsigned int v1 = *(const unsigned int*)(hb + (size_t)c1 * 128 + 2 * lane);
            unsigned int v2 = *(const unsigned int*)(hb + (size_t)c2 * 128 + 2 * lane);
            unsigned int v3 = *(const unsigned int*)(hb + (size_t)c3 * 128 + 2 * lane);
            float pA0 = sel4(pa.x, pa.y, pa.z, pa.w, hd);
            float pA1 = sel4(pb.x, pb.y, pb.z, pb.w, hd);
            float pA2 = sel4(pc.x, pc.y, pc.z, pc.w, hd);
            float pA3 = sel4(pq.x, pq.y, pq.z, pq.w, hd);
            acc0 += pA0 * bflo(v0) + pA1 * bflo(v1) + pA2 * bflo(v2) + pA3 * bflo(v3);
            acc1 += pA0 * bfhi(v0) + pA1 * bfhi(v1) + pA2 * bfhi(v2) + pA3 * bfhi(v3);
        }
    } else {
        // slow path: chunked two-pass (deg > 64 is astronomically rare)
        float m0 = NINF, m1 = NINF, m2 = NINF, m3 = NINF;
        for (int c = beg; c < end; c += 64) {
            int idx = c + lane;
            bool v = idx < end;
            if (v) {
                int col = col_idx[idx];
                float4 as4 = *(const float4*)(a_s + (size_t)col * 4);
                float e0 = as4.x + ad4.x; e0 = e0 > 0.f ? e0 : NEG_SLOPE * e0;
                float e1 = as4.y + ad4.y; e1 = e1 > 0.f ? e1 : NEG_SLOPE * e1;
                float e2 = as4.z + ad4.z; e2 = e2 > 0.f ? e2 : NEG_SLOPE * e2;
                float e3 = as4.w + ad4.w; e3 = e3 > 0.f ? e3 : NEG_SLOPE * e3;
                m0 = fmaxf(m0, e0); m1 = fmaxf(m1, e1);
                m2 = fmaxf(m2, e2); m3 = fmaxf(m3, e3);
            }
        }
#pragma unroll
        for (int off = 1; off < 64; off <<= 1) {
            m0 = fmaxf(m0, __shfl_xor(m0, off));
            m1 = fmaxf(m1, __shfl_xor(m1, off));
            m2 = fmaxf(m2, __shfl_xor(m2, off));
            m3 = fmaxf(m3, __shfl_xor(m3, off));
        }
        for (int c = beg; c < end; c += 64) {
            int idx = c + lane;
            bool v = idx < end;
            int col = v ? col_idx[idx] : 0;
            float p0 = 0.f, p1 = 0.f, p2 = 0.f, p3 = 0.f;
            if (v) {
                float4 as4 = *(const float4*)(a_s + (size_t)col * 4);
                float e0 = as4.x + ad4.x; e0 = e0 > 0.f ? e0 : NEG_SLOPE * e0;
                float e1 = as4.y + ad4.y; e1 = e1 > 0.f ? e1 : NEG_SLOPE * e1;
                float e2 = as4.z + ad4.z; e2 = e2 > 0.f ? e2 : NEG_SLOPE * e2;
                float e3 = as4.w + ad4.w; e3 = e3 > 0.f ? e3 : NEG_SLOPE * e3;
                p0 = __expf(e0 - m0); p1 = __expf(e1 - m1);
                p2 = __expf(e2 - m2); p3 = __expf(e3 - m3);
            }
            lpw[lane] = make_float4(p0, p1, p2, p3);
            lcw[lane] = col;
            float s0 = p0, s1 = p1, s2 = p2, s3 = p3;
#pragma unroll
            for (int off = 1; off < 64; off <<= 1) {
                s0 += __shfl_xor(s0, off); s1 += __shfl_xor(s1, off);
                s2 += __shfl_xor(s2, off); s3 += __shfl_xor(s3, off);
            }
            den0 += s0; den1 += s1; den2 += s2; den3 += s3;
            int csz = end - c; if (csz > 64) csz = 64;
            int cnt = (csz + 3) & ~3;
            for (int j = 0; j < cnt; j += 4) {
                float4 pa = lpw[j],     pb = lpw[j + 1];
                float4 pc = lpw[j + 2], pq = lpw[j + 3];
                int c0i = lcw[j], c1i = lcw[j + 1], c2i = lcw[j + 2], c3i = lcw[j + 3];
                unsigned int v0 = *(const unsigned int*)(hb + (size_t)c0i * 128 + 2 * lane);
                unsigned int v1 = *(const unsigned int*)(hb + (size_t)c1i * 128 + 2 * lane);
                unsigned int v2 = *(const unsigned int*)(hb + (size_t)c2i * 128 + 2 * lane);
                unsigned int v3 = *(const unsigned int*)(hb + (size_t)c3i * 128 + 2 * lane);
                float pA0 = sel4(pa.x, pa.y, pa.z, pa.w, hd);
                float pA1 = sel4(pb.x, pb.y, pb.z, pb.w, hd);
                float pA2 = sel4(pc.x, pc.y, pc.z, pc.w, hd);
                float pA3 = sel4(pq.x, pq.y, pq.z, pq.w, hd);
                acc0 += pA0 * bflo(v0) + pA1 * bflo(v1) + pA2 * bflo(v2) + pA3 * bflo(v3);
                acc1 += pA0 * bfhi(v0) + pA1 * bfhi(v1) + pA2 * bfhi(v2) + pA3 * bfhi(v3);
            }
        }
    }

    float dsel = sel4(den0, den1, den2, den3, hd);
    float inv = 1.f / (dsel + 1e-16f);
    float f0 = acc0 * inv;
    float f1 = acc1 * inv;
    const int fA = lane * 2;
    float2 bb  = *(const float2*)(b + fA);
    float2 gg  = *(const float2*)(g + fA);
    float2 be  = *(const float2*)(beta + fA);
    float2 rmm = *(const float2*)(rm + fA);
    float2 rvv = *(const float2*)(rv + fA);
    f0 = (f0 + bb.x - rmm.x) * rsqrtf(rvv.x + BN_EPS) * gg.x + be.x;
    f1 = (f1 + bb.y - rmm.y) * rsqrtf(rvv.y + BN_EPS) * gg.y + be.y;
    f0 = f0 > 0.f ? f0 : (__expf(f0) - 1.f);
    f1 = f1 > 0.f ? f1 : (__expf(f1) - 1.f);
    *(float2*)(obuf + (size_t)n * 128 + fA) = make_float2(f0, f1);
}

// layer2: 1 head, C=32. 1 wave/node; gather does 8 edges/iter (4 per half),
// folded by shfl_xor(acc,32) at the end.
__global__ __launch_bounds__(256) void k_agg2(const float* __restrict__ h,
                                              const float* __restrict__ a_s,
                                              const float* __restrict__ a_d,
                                              const int* __restrict__ row_ptr,
                                              const int* __restrict__ col_idx,
                                              const float* __restrict__ b,
                                              const float* __restrict__ g,
                                              const float* __restrict__ beta,
                                              const float* __restrict__ rm,
                                              const float* __restrict__ rv,
                                              float* __restrict__ obuf) {
    __shared__ float lp[4 * 64];
    __shared__ int   lc[4 * 64];
    const int wid  = threadIdx.x >> 6;
    const int lane = threadIdx.x & 63;
    const int n = (blockIdx.x << 2) + wid;
    if (n >= N_NODES) return;
    float* lpw = lp + (wid << 6);
    int*   lcw = lc + (wid << 6);
    const int l31 = lane & 31, hh = lane >> 5;
    const float ad = a_d[n];
    const int beg = row_ptr[n], end = row_ptr[n + 1];
    const int deg = end - beg;
    float den = 0.f, acc = 0.f;

    if (deg <= 64) {
        const int idx = beg + lane;
        const bool v = idx < end;
        const int col = v ? col_idx[idx] : 0;
        float e = NINF;
        if (v) {
            e = a_s[col] + ad;
            e = e > 0.f ? e : NEG_SLOPE * e;
        }
        float m = e;
#pragma unroll
        for (int off = 1; off < 64; off <<= 1) m = fmaxf(m, __shfl_xor(m, off));
        float p = __expf(e - m);
        lpw[lane] = p;
        lcw[lane] = col;
        den = p;
#pragma unroll
        for (int off = 1; off < 64; off <<= 1) den += __shfl_xor(den, off);
        const int cnt = (deg + 7) & ~7;
        for (int j = 0; j < cnt; j += 8) {
            int j0 = j + (hh << 2);
            float p0 = lpw[j0], p1 = lpw[j0 + 1], p2 = lpw[j0 + 2], p3 = lpw[j0 + 3];
            int c0 = lcw[j0], c1 = lcw[j0 + 1], c2 = lcw[j0 + 2], c3 = lcw[j0 + 3];
            acc += p0 * h[(size_t)c0 * 32 + l31] + p1 * h[(size_t)c1 * 32 + l31]
                 + p2 * h[(size_t)c2 * 32 + l31] + p3 * h[(size_t)c3 * 32 + l31];
        }
    } else {
        float m = NINF;
        for (int c = beg; c < end; c += 64) {
            int idx = c + lane;
            if (idx < end) {
                float e = a_s[col_idx[idx]] + ad;
                e = e > 0.f ? e : NEG_SLOPE * e;
                m = fmaxf(m, e);
            }
        }
#pragma unroll
        for (int off = 1; off < 64; off <<= 1) m = fmaxf(m, __shfl_xor(m, off));
        for (int c = beg; c < end; c += 64) {
            int idx = c + lane;
            bool v = idx < end;
            int col = v ? col_idx[idx] : 0;
            float p = 0.f;
            if (v) {
                float e = a_s[col] + ad;
                e = e > 0.f ? e : NEG_SLOPE * e;
                p = __expf(e - m);
            }
            lpw[lane] = p;
            lcw[lane] = col;
            float s = p;
#pragma unroll
            for (int off = 1; off < 64; off <<= 1) s += __shfl_xor(s, off);
            den += s;
            int csz = end - c; if (csz > 64) csz = 64;
            int cnt = (csz + 7) & ~7;
            for (int j = 0; j < cnt; j += 8) {
                int j0 = j + (hh << 2);
                float p0 = lpw[j0], p1 = lpw[j0 + 1], p2 = lpw[j0 + 2], p3 = lpw[j0 + 3];
                int c0 = lcw[j0], c1 = lcw[j0 + 1], c2 = lcw[j0 + 2], c3 = lcw[j0 + 3];
                acc += p0 * h[(size_t)c0 * 32 + l31] + p1 * h[(size_t)c1 * 32 + l31]
                     + p2 * h[(size_t)c2 * 32 + l31] + p3 * h[(size_t)c3 * 32 + l31];
            }
        }
    }
    acc += __shfl_xor(acc, 32);
    float vout = acc / (den + 1e-16f);
    vout += b[l31];
    vout = (vout - rm[l31]) * rsqrtf(rv[l31] + BN_EPS) * g[l31] + beta[l31];
    vout = vout > 0.f ? vout : (__expf(vout) - 1.f);
    if (lane < 32) obuf[(size_t)n * 32 + lane] = vout;
}

// layer3: 1 head, C=40. 1 wave/node; fused bias + log_softmax.
__global__ __launch_bounds__(256) void k_agg3(const float* __restrict__ h,
                                              const float* __restrict__ a_s,
                                              const float* __restrict__ a_d,
                                              const int* __restrict__ row_ptr,
                                              const int* __restrict__ col_idx,
                                              const float* __restrict__ b,
                                              float* __restrict__ out) {
    __shared__ float lp[4 * 64];
    __shared__ int   lc[4 * 64];
    const int wid  = threadIdx.x >> 6;
    const int lane = threadIdx.x & 63;
    const int n = (blockIdx.x << 2) + wid;
    if (n >= N_NODES) return;
    float* lpw = lp + (wid << 6);
    int*   lcw = lc + (wid << 6);
    const float ad = a_d[n];
    const int beg = row_ptr[n], end = row_ptr[n + 1];
    const int deg = end - beg;
    float den = 0.f, acc = 0.f;

    if (deg <= 64) {
        const int idx = beg + lane;
        const bool v = idx < end;
        const int col = v ? col_idx[idx] : 0;
        float e = NINF;
        if (v) {
            e = a_s[col] + ad;
            e = e > 0.f ? e : NEG_SLOPE * e;
        }
        float m = e;
#pragma unroll
        for (int off = 1; off < 64; off <<= 1) m = fmaxf(m, __shfl_xor(m, off));
        float p = __expf(e - m);
        lpw[lane] = p;
        lcw[lane] = col;
        den = p;
#pragma unroll
        for (int off = 1; off < 64; off <<= 1) den += __shfl_xor(den, off);
        const int cnt = (deg + 3) & ~3;
        for (int j = 0; j < cnt; j += 4) {
            float p0 = lpw[j], p1 = lpw[j + 1], p2 = lpw[j + 2], p3 = lpw[j + 3];
            int c0 = lcw[j], c1 = lcw[j + 1], c2 = lcw[j + 2], c3 = lcw[j + 3];
            if (lane < 40) {
                acc += p0 * h[(size_t)c0 * 40 + lane] + p1 * h[(size_t)c1 * 40 + lane]
                     + p2 * h[(size_t)c2 * 40 + lane] + p3 * h[(size_t)c3 * 40 + lane];
            }
        }
    } else {
        float m = NINF;
        for (int c = beg; c < end; c += 64) {
            int idx = c + lane;
            if (idx < end) {
                float e = a_s[col_idx[idx]] + ad;
                e = e > 0.f ? e : NEG_SLOPE * e;
                m = fmaxf(m, e);
            }
        }
#pragma unroll
        for (int off = 1; off < 64; off <<= 1) m = fmaxf(m, __shfl_xor(m, off));
        for (int c = beg; c < end; c += 64) {
            int idx = c + lane;
            bool v = idx < end;
            int col = v ? col_idx[idx] : 0;
            float p = 0.f;
            if (v) {
                float e = a_s[col] + ad;
                e = e > 0.f ? e : NEG_SLOPE * e;
                p = __expf(e - m);
            }
            lpw[lane] = p;
            lcw[lane] = col;
            float s = p;
#pragma unroll
            for (int off = 1; off < 64; off <<= 1) s += __shfl_xor(s, off);
            den += s;
            int csz = end - c; if (csz > 64) csz = 64;
            int cnt = (csz + 3) & ~3;
            for (int j = 0; j < cnt; j += 4) {
                float p0 = lpw[j], p1 = lpw[j + 1], p2 = lpw[j + 2], p3 = lpw[j + 3];
                int c0 = lcw[j], c1 = lcw[j + 1], c2 = lcw[j + 2], c3 = lcw[j + 3];
                if (lane < 40) {
                    acc += p0 * h[(size_t)c0 * 40 + lane] + p1 * h[(size_t)c1 * 40 + lane]
                         + p2 * h[(size_t)c2 * 40 + lane] + p3 * h[(size_t)c3 * 40 + lane];
                }
            }
        }
    }
    float vv = acc / (den + 1e-16f) + b[lane < 40 ? lane : 0];
    float vm = (lane < 40) ? vv : NINF;
#pragma unroll
    for (int off = 1; off < 64; off <<= 1) vm = fmaxf(vm, __shfl_xor(vm, off));
    float ex = (lane < 40) ? __expf(vv - vm) : 0.f;
#pragma unroll
    for (int off = 1; off < 64; off <<= 1) ex += __shfl_xor(ex, off);
    float res = vv - vm - logf(ex);
    if (lane < 40) out[(size_t)n * 40 + lane] = res;
}

// ---------------------------------------------------------------- launch

extern "C" void kernel_launch(void* const* d_in, const int* in_sizes, int n_in,
                              void* d_out, int out_size, void* d_ws, size_t ws_size,
                              hipStream_t stream) {
    const float* x    = (const float*)d_in[0];
    const int*   ei   = (const int*)d_in[1];
    const float* W1   = (const float*)d_in[2];
    const float* as1  = (const float*)d_in[3];
    const float* ad1  = (const float*)d_in[4];
    const float* b1   = (const float*)d_in[5];
    const float* g1   = (const float*)d_in[6];
    const float* be1  = (const float*)d_in[7];
    const float* rm1  = (const float*)d_in[8];
    const float* rv1  = (const float*)d_in[9];
    const float* W2   = (const float*)d_in[10];
    const float* as2  = (const float*)d_in[11];
    const float* ad2  = (const float*)d_in[12];
    const float* b2   = (const float*)d_in[13];
    const float* g2   = (const float*)d_in[14];
    const float* be2  = (const float*)d_in[15];
    const float* rm2  = (const float*)d_in[16];
    const float* rv2  = (const float*)d_in[17];
    const float* W3   = (const float*)d_in[18];
    const float* as3  = (const float*)d_in[19];
    const float* ad3  = (const float*)d_in[20];
    const float* b3   = (const float*)d_in[21];
    float* out = (float*)d_out;

    char* base = (char*)d_ws;
    size_t off = 0;
    auto carve = [&](size_t bytes) {
        char* p = base + off;
        off = (off + bytes + 255) & ~(size_t)255;
        return p;
    };
    int*   row_ptr = (int*)carve((N_NODES + 1) * sizeof(int));
    int*   cnt     = (int*)carve(N_NODES * sizeof(int));
    int*   cursor  = (int*)carve(N_NODES * sizeof(int));
    int*   sums    = (int*)carve(1024 * sizeof(int));
    int*   col_idx = (int*)carve((size_t)E_TOT * sizeof(int));
    float* a_s     = (float*)carve((size_t)N_NODES * 4 * sizeof(float));
    float* a_d     = (float*)carve((size_t)N_NODES * 4 * sizeof(float));
    float* hbuf    = (float*)carve((size_t)N_NODES * 128 * sizeof(float));
    float* obuf    = (float*)carve((size_t)N_NODES * 128 * sizeof(float));
    (void)ws_size;

    hipMemsetAsync(cnt, 0, N_NODES * sizeof(int), stream);
    {
        int g1b = (E_TOT + 255) / 256;
        k_count<<<g1b, 256, 0, stream>>>(ei, cnt);
        int nb = (N_NODES + 1023) / 1024;
        k_scan1<<<nb, 256, 0, stream>>>(cnt, row_ptr, sums);
        k_scan2<<<1, 1, 0, stream>>>(sums, nb);
        k_scan3<<<(N_NODES + 255) / 256, 256, 0, stream>>>(row_ptr, cursor, sums);
        k_scatter<<<g1b, 256, 0, stream>>>(ei, cursor, col_idx);
    }

    const int GEMM_GRID = (N_NODES + 63) / 64;
    const int WPN = (N_NODES + 3) / 4;

    // layer1: GEMM + fused attproj (4 heads), bf16 h for the gather
    k_gemm_ap<128, 128, 64, 256, 4, true><<<GEMM_GRID, 256, 0, stream>>>(
        x, W1, as1, ad1, a_s, a_d, (void*)hbuf, N_NODES);
    k_agg1<<<WPN, 256, 0, stream>>>((const unsigned short*)hbuf, a_s, a_d,
                                    row_ptr, col_idx,
                                    b1, g1, be1, rm1, rv1, obuf);

    // layer2: GEMM + fused attproj (1 head), fp32 h
    k_gemm_ap<128, 32, 64, 256, 1, false><<<GEMM_GRID, 256, 0, stream>>>(
        obuf, W2, as2, ad2, a_s, a_d, (void*)hbuf, N_NODES);
    k_agg2<<<WPN, 256, 0, stream>>>(hbuf, a_s, a_d, row_ptr, col_idx,
                                    b2, g2, be2, rm2, rv2, obuf);

    // layer3: plain GEMM (40 cols -> 10-lane groups, no clean shuffle fusion)
    k_gemm<32, 40, 64, 320><<<GEMM_GRID, 320, 0, stream>>>(obuf, W3, hbuf, N_NODES);
    k_attproj3<<<WPN, 256, 0, stream>>>(hbuf, as3, ad3, a_s, a_d);
    k_agg3<<<WPN, 256, 0, stream>>>(hbuf, a_s, a_d, row_ptr, col_idx, b3, out);
}

// Round 13
// 635.813 us; speedup vs baseline: 1.5219x; 1.0457x over previous
//
#include <hip/hip_runtime.h>
#include <math.h>

#define N_NODES 100000
#define N_EDGES 1600000
#define E_TOT   (N_EDGES + N_NODES)
#define BN_EPS  1e-5f
#define NEG_SLOPE 0.2f
#define NINF (-INFINITY)

// binned-scatter parameters
#define NPB   2048                              // nodes per bucket (2^11)
#define NBUCK ((N_NODES + NPB - 1) / NPB)       // 49
#define EPB   4096                              // edges per stage block

// bf16 helpers (manual, RNE)
__device__ __forceinline__ unsigned short f2bf(float f) {
    unsigned int u = __float_as_uint(f);
    unsigned int r = (u + 0x7FFFu + ((u >> 16) & 1u)) >> 16;
    return (unsigned short)r;
}
__device__ __forceinline__ float bflo(unsigned int v) {
    return __uint_as_float(v << 16);
}
__device__ __forceinline__ float bfhi(unsigned int v) {
    return __uint_as_float(v & 0xFFFF0000u);
}
__device__ __forceinline__ float sel4(float a, float b, float c, float d, int i) {
    float lo = (i & 1) ? b : a;
    float hi = (i & 1) ? d : c;
    return (i & 2) ? hi : lo;
}

// ---------------------------------------------------------------- CSR: row_ptr

__global__ __launch_bounds__(256) void k_count(const int* __restrict__ ei,
                                               int* __restrict__ cnt) {
    int i = blockIdx.x * blockDim.x + threadIdx.x;
    if (i >= E_TOT) return;
    int d = (i < N_EDGES) ? ei[N_EDGES + i] : (i - N_EDGES);
    atomicAdd(&cnt[d], 1);
}

__global__ __launch_bounds__(256) void k_scan1(const int* __restrict__ cnt,
                                               int* __restrict__ excl,
                                               int* __restrict__ sums) {
    __shared__ int lds[256];
    int t = threadIdx.x;
    int base = blockIdx.x * 1024 + t * 4;
    int a[4];
#pragma unroll
    for (int j = 0; j < 4; ++j) a[j] = (base + j < N_NODES) ? cnt[base + j] : 0;
    int tot = a[0] + a[1] + a[2] + a[3];
    lds[t] = tot;
    __syncthreads();
    for (int off = 1; off < 256; off <<= 1) {
        int v = (t >= off) ? lds[t - off] : 0;
        __syncthreads();
        lds[t] += v;
        __syncthreads();
    }
    int run = lds[t] - tot;
#pragma unroll
    for (int j = 0; j < 4; ++j) {
        if (base + j < N_NODES) excl[base + j] = run;
        run += a[j];
    }
    if (t == 255) sums[blockIdx.x] = lds[255];
}

__global__ void k_scan2(int* sums, int nb) {
    if (blockIdx.x == 0 && threadIdx.x == 0) {
        int run = 0;
        for (int i = 0; i < nb; ++i) { int v = sums[i]; sums[i] = run; run += v; }
    }
}

__global__ __launch_bounds__(256) void k_scan3(int* __restrict__ row_ptr,
                                               const int* __restrict__ sums) {
    int i = blockIdx.x * blockDim.x + threadIdx.x;
    if (i == 0) row_ptr[N_NODES] = E_TOT;
    if (i >= N_NODES) return;
    row_ptr[i] += sums[i >> 10];
}

// ---------------------------------------------------------------- CSR: binned col_idx
// Two-level scatter: stage edges into bucket-contiguous packed records
// (coalesced writes), then one block per bucket resolves final positions —
// all writes to a bucket's col_idx window come from ONE CU -> one XCD L2 ->
// full-line write combining (fixes the 64B-line-per-4B-store amplification).

__global__ __launch_bounds__(256) void kb_hist(const int* __restrict__ ei,
                                               int* __restrict__ bucket_cnt) {
    __shared__ int h[NBUCK];
    for (int t = threadIdx.x; t < NBUCK; t += 256) h[t] = 0;
    __syncthreads();
    const int base = blockIdx.x * EPB;
#pragma unroll
    for (int j = 0; j < EPB / 256; ++j) {
        int i = base + j * 256 + threadIdx.x;
        if (i < E_TOT) {
            int d = (i < N_EDGES) ? ei[N_EDGES + i] : (i - N_EDGES);
            atomicAdd(&h[d >> 11], 1);
        }
    }
    __syncthreads();
    for (int t = threadIdx.x; t < NBUCK; t += 256)
        if (h[t]) atomicAdd(&bucket_cnt[t], h[t]);
}

__global__ void kb_scan(const int* __restrict__ bucket_cnt,
                        int* __restrict__ bucket_base,
                        int* __restrict__ bucket_cursor) {
    if (blockIdx.x == 0 && threadIdx.x == 0) {
        int run = 0;
        for (int b = 0; b < NBUCK; ++b) {
            bucket_base[b] = run;
            bucket_cursor[b] = run;
            run += bucket_cnt[b];
        }
        bucket_base[NBUCK] = run;
    }
}

__global__ __launch_bounds__(256) void kb_stage(const int* __restrict__ ei,
                                                int* __restrict__ bucket_cursor,
                                                unsigned int* __restrict__ estage) {
    __shared__ int h[NBUCK], base_l[NBUCK], cnt2[NBUCK], gbase[NBUCK];
    __shared__ unsigned int recs[EPB];
    for (int t = threadIdx.x; t < NBUCK; t += 256) { h[t] = 0; cnt2[t] = 0; }
    __syncthreads();
    const int base = blockIdx.x * EPB;
    int myb[EPB / 256];
    unsigned int myrec[EPB / 256];
#pragma unroll
    for (int j = 0; j < EPB / 256; ++j) {
        int i = base + j * 256 + threadIdx.x;
        myb[j] = -1;
        myrec[j] = 0;
        if (i < E_TOT) {
            int s, d;
            if (i < N_EDGES) { s = ei[i]; d = ei[N_EDGES + i]; }
            else             { s = d = i - N_EDGES; }
            int b = d >> 11;
            myb[j] = b;
            myrec[j] = ((unsigned int)(d & (NPB - 1)) << 17) | (unsigned int)s;
            atomicAdd(&h[b], 1);
        }
    }
    __syncthreads();
    if (threadIdx.x == 0) {
        int run = 0;
        for (int b = 0; b < NBUCK; ++b) { base_l[b] = run; run += h[b]; }
    }
    __syncthreads();
    for (int t = threadIdx.x; t < NBUCK; t += 256)
        gbase[t] = h[t] ? atomicAdd(&bucket_cursor[t], h[t]) : 0;
    // group records by bucket in LDS
#pragma unroll
    for (int j = 0; j < EPB / 256; ++j) {
        if (myb[j] >= 0) {
            int pos = base_l[myb[j]] + atomicAdd(&cnt2[myb[j]], 1);
            recs[pos] = myrec[j];
        }
    }
    __syncthreads();
    int m = E_TOT - base; if (m > EPB) m = EPB;
    for (int i = threadIdx.x; i < m; i += 256) {
        // largest b with base_l[b] <= i (empty buckets collapse onto next)
        int lo = 0, hi = NBUCK - 1;
        while (lo < hi) {
            int mid = (lo + hi + 1) >> 1;
            if (base_l[mid] <= i) lo = mid; else hi = mid - 1;
        }
        estage[gbase[lo] + (i - base_l[lo])] = recs[i];
    }
}

__global__ __launch_bounds__(256) void kb_scatter(const unsigned int* __restrict__ estage,
                                                  const int* __restrict__ bucket_base,
                                                  const int* __restrict__ row_ptr,
                                                  int* __restrict__ col_idx) {
    __shared__ int cur[NPB];
    const int b = blockIdx.x;
    const int n0 = b * NPB;
    int nn = N_NODES - n0; if (nn > NPB) nn = NPB;
    for (int i = threadIdx.x; i < nn; i += 256) cur[i] = row_ptr[n0 + i];
    __syncthreads();
    const int e1 = bucket_base[b + 1];
    for (int i = bucket_base[b] + threadIdx.x; i < e1; i += 256) {
        unsigned int r = estage[i];
        int dl = (int)(r >> 17);
        int s  = (int)(r & 0x1FFFFu);
        int pos = atomicAdd(&cur[dl], 1);
        col_idx[pos] = s;
    }
}

// ---------------------------------------------------------------- GEMM (plain)

template <int K, int NC, int BM, int BLOCK>
__global__ __launch_bounds__(BLOCK) void k_gemm(const float* __restrict__ X,
                                                const float* __restrict__ W,
                                                float* __restrict__ Hout,
                                                int nrows) {
    constexpr int CG  = NC / 4;
    constexpr int TR  = BLOCK / CG;
    constexpr int RPT = BM / TR;
    constexpr int LDK = K + 4;
    __shared__ float xs[BM * LDK];
    const int row0 = blockIdx.x * BM;
    const int vr = (nrows - row0 < BM) ? (nrows - row0) : BM;
    const int nvalid = vr * K;
    for (int i = threadIdx.x * 4; i < BM * K; i += BLOCK * 4) {
        float4 v = make_float4(0.f, 0.f, 0.f, 0.f);
        if (i < nvalid) v = *(const float4*)(X + (size_t)row0 * K + i);
        int row = i / K, col = i % K;
        *(float4*)(&xs[row * LDK + col]) = v;
    }
    __syncthreads();
    const int tx = threadIdx.x % CG;
    const int ty = threadIdx.x / CG;
    float4 acc[RPT];
#pragma unroll
    for (int r = 0; r < RPT; ++r) acc[r] = make_float4(0.f, 0.f, 0.f, 0.f);
    for (int k4 = 0; k4 < K / 4; ++k4) {
        const float4 w0 = *(const float4*)(W + (k4 * 4 + 0) * NC + tx * 4);
        const float4 w1 = *(const float4*)(W + (k4 * 4 + 1) * NC + tx * 4);
        const float4 w2 = *(const float4*)(W + (k4 * 4 + 2) * NC + tx * 4);
        const float4 w3 = *(const float4*)(W + (k4 * 4 + 3) * NC + tx * 4);
#pragma unroll
        for (int r = 0; r < RPT; ++r) {
            const float4 xv = *(const float4*)(&xs[(ty * RPT + r) * LDK + k4 * 4]);
            acc[r].x = fmaf(xv.w, w3.x, fmaf(xv.z, w2.x, fmaf(xv.y, w1.x, fmaf(xv.x, w0.x, acc[r].x))));
            acc[r].y = fmaf(xv.w, w3.y, fmaf(xv.z, w2.y, fmaf(xv.y, w1.y, fmaf(xv.x, w0.y, acc[r].y))));
            acc[r].z = fmaf(xv.w, w3.z, fmaf(xv.z, w2.z, fmaf(xv.y, w1.z, fmaf(xv.x, w0.z, acc[r].z))));
            acc[r].w = fmaf(xv.w, w3.w, fmaf(xv.z, w2.w, fmaf(xv.y, w1.w, fmaf(xv.x, w0.w, acc[r].w))));
        }
    }
#pragma unroll
    for (int r = 0; r < RPT; ++r) {
        int row = row0 + ty * RPT + r;
        if (row < nrows) *(float4*)(Hout + (size_t)row * NC + tx * 4) = acc[r];
    }
}

// ------------------------------------------------ GEMM + fused attention proj

template <int K, int NC, int BM, int BLOCK, int HEADS_, bool BF16OUT>
__global__ __launch_bounds__(BLOCK) void k_gemm_ap(const float* __restrict__ X,
                                                   const float* __restrict__ W,
                                                   const float* __restrict__ asf,
                                                   const float* __restrict__ adf,
                                                   float* __restrict__ a_s,
                                                   float* __restrict__ a_d,
                                                   void* __restrict__ Hout,
                                                   int nrows) {
    constexpr int CG  = NC / 4;
    constexpr int TR  = BLOCK / CG;
    constexpr int RPT = BM / TR;
    constexpr int LDK = K + 4;
    constexpr int GL  = NC / HEADS_ / 4;
    static_assert(GL == 8, "epilogue assumes 8-lane groups");
    __shared__ float xs[BM * LDK];
    const int row0 = blockIdx.x * BM;
    const int vr = (nrows - row0 < BM) ? (nrows - row0) : BM;
    const int nvalid = vr * K;
    for (int i = threadIdx.x * 4; i < BM * K; i += BLOCK * 4) {
        float4 v = make_float4(0.f, 0.f, 0.f, 0.f);
        if (i < nvalid) v = *(const float4*)(X + (size_t)row0 * K + i);
        int row = i / K, col = i % K;
        *(float4*)(&xs[row * LDK + col]) = v;
    }
    __syncthreads();
    const int tx = threadIdx.x % CG;
    const int ty = threadIdx.x / CG;
    float4 acc[RPT];
#pragma unroll
    for (int r = 0; r < RPT; ++r) acc[r] = make_float4(0.f, 0.f, 0.f, 0.f);
    for (int k4 = 0; k4 < K / 4; ++k4) {
        const float4 w0 = *(const float4*)(W + (k4 * 4 + 0) * NC + tx * 4);
        const float4 w1 = *(const float4*)(W + (k4 * 4 + 1) * NC + tx * 4);
        const float4 w2 = *(const float4*)(W + (k4 * 4 + 2) * NC + tx * 4);
        const float4 w3 = *(const float4*)(W + (k4 * 4 + 3) * NC + tx * 4);
#pragma unroll
        for (int r = 0; r < RPT; ++r) {
            const float4 xv = *(const float4*)(&xs[(ty * RPT + r) * LDK + k4 * 4]);
            acc[r].x = fmaf(xv.w, w3.x, fmaf(xv.z, w2.x, fmaf(xv.y, w1.x, fmaf(xv.x, w0.x, acc[r].x))));
            acc[r].y = fmaf(xv.w, w3.y, fmaf(xv.z, w2.y, fmaf(xv.y, w1.y, fmaf(xv.x, w0.y, acc[r].y))));
            acc[r].z = fmaf(xv.w, w3.z, fmaf(xv.z, w2.z, fmaf(xv.y, w1.z, fmaf(xv.x, w0.z, acc[r].z))));
            acc[r].w = fmaf(xv.w, w3.w, fmaf(xv.z, w2.w, fmaf(xv.y, w1.w, fmaf(xv.x, w0.w, acc[r].w))));
        }
    }
    const int head = tx >> 3;
    const float4 asv = *(const float4*)(asf + tx * 4);
    const float4 adv = *(const float4*)(adf + tx * 4);
#pragma unroll
    for (int r = 0; r < RPT; ++r) {
        int row = row0 + ty * RPT + r;
        float ps = acc[r].x * asv.x + acc[r].y * asv.y + acc[r].z * asv.z + acc[r].w * asv.w;
        float pd = acc[r].x * adv.x + acc[r].y * adv.y + acc[r].z * adv.z + acc[r].w * adv.w;
#pragma unroll
        for (int off = 1; off < GL; off <<= 1) {
            ps += __shfl_xor(ps, off);
            pd += __shfl_xor(pd, off);
        }
        if (row < nrows) {
            if constexpr (BF16OUT) {
                ushort4 o;
                o.x = f2bf(acc[r].x); o.y = f2bf(acc[r].y);
                o.z = f2bf(acc[r].z); o.w = f2bf(acc[r].w);
                *(ushort4*)((unsigned short*)Hout + (size_t)row * NC + tx * 4) = o;
            } else {
                *(float4*)((float*)Hout + (size_t)row * NC + tx * 4) = acc[r];
            }
            if ((tx & (GL - 1)) == 0) {
                a_s[(size_t)row * HEADS_ + head] = ps;
                a_d[(size_t)row * HEADS_ + head] = pd;
            }
        }
    }
}

// ---------------------------------------------------------------- attproj3

__global__ __launch_bounds__(256) void k_attproj3(const float* __restrict__ h,
                                                  const float* __restrict__ asf,
                                                  const float* __restrict__ adf,
                                                  float* __restrict__ a_s,
                                                  float* __restrict__ a_d) {
    int wv = (blockIdx.x * blockDim.x + threadIdx.x) >> 6;
    int lane = threadIdx.x & 63;
    if (wv >= N_NODES) return;
    float hv = (lane < 40) ? h[(size_t)wv * 40 + lane] : 0.f;
    float s = (lane < 40) ? hv * asf[lane] : 0.f;
    float d = (lane < 40) ? hv * adf[lane] : 0.f;
#pragma unroll
    for (int off = 1; off < 64; off <<= 1) { s += __shfl_xor(s, off); d += __shfl_xor(d, off); }
    if (lane == 0) { a_s[wv] = s; a_d[wv] = d; }
}

// ---------------------------------------------------------------- aggregation

// layer1: H=4, C=32 (128 feats), bf16 h. Lane owns feats {2*lane, 2*lane+1}.
__global__ __launch_bounds__(256) void k_agg1(const unsigned short* __restrict__ hb,
                                              const float* __restrict__ a_s,
                                              const float* __restrict__ a_d,
                                              const int* __restrict__ row_ptr,
                                              const int* __restrict__ col_idx,
                                              const float* __restrict__ b,
                                              const float* __restrict__ g,
                                              const float* __restrict__ beta,
                                              const float* __restrict__ rm,
                                              const float* __restrict__ rv,
                                              float* __restrict__ obuf) {
    __shared__ float4 lp[4 * 64];
    __shared__ int    lc[4 * 64];
    const int wid  = threadIdx.x >> 6;
    const int lane = threadIdx.x & 63;
    const int n = (blockIdx.x << 2) + wid;
    if (n >= N_NODES) return;
    float4* lpw = lp + (wid << 6);
    int*    lcw = lc + (wid << 6);
    const int hd = lane >> 4;
    const float4 ad4 = *(const float4*)(a_d + (size_t)n * 4);
    const int beg = row_ptr[n], end = row_ptr[n + 1];
    const int deg = end - beg;
    float den0 = 0.f, den1 = 0.f, den2 = 0.f, den3 = 0.f;
    float acc0 = 0.f, acc1 = 0.f;

    if (deg <= 64) {
        const int idx = beg + lane;
        const bool v = idx < end;
        const int col = v ? col_idx[idx] : 0;
        float e0, e1, e2, e3;
        if (v) {
            float4 as4 = *(const float4*)(a_s + (size_t)col * 4);
            e0 = as4.x + ad4.x; e0 = e0 > 0.f ? e0 : NEG_SLOPE * e0;
            e1 = as4.y + ad4.y; e1 = e1 > 0.f ? e1 : NEG_SLOPE * e1;
            e2 = as4.z + ad4.z; e2 = e2 > 0.f ? e2 : NEG_SLOPE * e2;
            e3 = as4.w + ad4.w; e3 = e3 > 0.f ? e3 : NEG_SLOPE * e3;
        } else { e0 = e1 = e2 = e3 = NINF; }
        float m0 = e0, m1 = e1, m2 = e2, m3 = e3;
#pragma unroll
        for (int off = 1; off < 64; off <<= 1) {
            m0 = fmaxf(m0, __shfl_xor(m0, off));
            m1 = fmaxf(m1, __shfl_xor(m1, off));
            m2 = fmaxf(m2, __shfl_xor(m2, off));
            m3 = fmaxf(m3, __shfl_xor(m3, off));
        }
        float p0 = __expf(e0 - m0), p1 = __expf(e1 - m1);
        float p2 = __expf(e2 - m2), p3 = __expf(e3 - m3);
        lpw[lane] = make_float4(p0, p1, p2, p3);
        lcw[lane] = col;
        den0 = p0; den1 = p1; den2 = p2; den3 = p3;
#pragma unroll
        for (int off = 1; off < 64; off <<= 1) {
            den0 += __shfl_xor(den0, off); den1 += __shfl_xor(den1, off);
            den2 += __shfl_xor(den2, off); den3 += __shfl_xor(den3, off);
        }
        const int cnt = (deg + 3) & ~3;
        for (int j = 0; j < cnt; j += 4) {
            float4 pa = lpw[j],     pb = lpw[j + 1];
            float4 pc = lpw[j + 2], pq = lpw[j + 3];
            int c0 = lcw[j], c1 = lcw[j + 1], c2 = lcw[j + 2], c3 = lcw[j + 3];
            unsigned int v0 = *(const unsigned int*)(hb + (size_t)c0 * 128 + 2 * lane);
            unsigned int v1 = *(const unsigned int*)(hb + (size_t)c1 * 128 + 2 * lane);
            unsigned int v2 = *(const unsigned int*)(hb + (size_t)c2 * 128 + 2 * lane);
            unsigned int v3 = *(const unsigned int*)(hb + (size_t)c3 * 128 + 2 * lane);
            float pA0 = sel4(pa.x, pa.y, pa.z, pa.w, hd);
            float pA1 = sel4(pb.x, pb.y, pb.z, pb.w, hd);
            float pA2 = sel4(pc.x, pc.y, pc.z, pc.w, hd);
            float pA3 = sel4(pq.x, pq.y, pq.z, pq.w, hd);
            acc0 += pA0 * bflo(v0) + pA1 * bflo(v1) + pA2 * bflo(v2) + pA3 * bflo(v3);
            acc1 += pA0 * bfhi(v0) + pA1 * bfhi(v1) + pA2 * bfhi(v2) + pA3 * bfhi(v3);
        }
    } else {
        float m0 = NINF, m1 = NINF, m2 = NINF, m3 = NINF;
        for (int c = beg; c < end; c += 64) {
            int idx = c + lane;
            bool v = idx < end;
            if (v) {
                int col = col_idx[idx];
                float4 as4 = *(const float4*)(a_s + (size_t)col * 4);
                float e0 = as4.x + ad4.x; e0 = e0 > 0.f ? e0 : NEG_SLOPE * e0;
                float e1 = as4.y + ad4.y; e1 = e1 > 0.f ? e1 : NEG_SLOPE * e1;
                float e2 = as4.z + ad4.z; e2 = e2 > 0.f ? e2 : NEG_SLOPE * e2;
                float e3 = as4.w + ad4.w; e3 = e3 > 0.f ? e3 : NEG_SLOPE * e3;
                m0 = fmaxf(m0, e0); m1 = fmaxf(m1, e1);
                m2 = fmaxf(m2, e2); m3 = fmaxf(m3, e3);
            }
        }
#pragma unroll
        for (int off = 1; off < 64; off <<= 1) {
            m0 = fmaxf(m0, __shfl_xor(m0, off));
            m1 = fmaxf(m1, __shfl_xor(m1, off));
            m2 = fmaxf(m2, __shfl_xor(m2, off));
            m3 = fmaxf(m3, __shfl_xor(m3, off));
        }
        for (int c = beg; c < end; c += 64) {
            int idx = c + lane;
            bool v = idx < end;
            int col = v ? col_idx[idx] : 0;
            float p0 = 0.f, p1 = 0.f, p2 = 0.f, p3 = 0.f;
            if (v) {
                float4 as4 = *(const float4*)(a_s + (size_t)col * 4);
                float e0 = as4.x + ad4.x; e0 = e0 > 0.f ? e0 : NEG_SLOPE * e0;
                float e1 = as4.y + ad4.y; e1 = e1 > 0.f ? e1 : NEG_SLOPE * e1;
                float e2 = as4.z + ad4.z; e2 = e2 > 0.f ? e2 : NEG_SLOPE * e2;
                float e3 = as4.w + ad4.w; e3 = e3 > 0.f ? e3 : NEG_SLOPE * e3;
                p0 = __expf(e0 - m0); p1 = __expf(e1 - m1);
                p2 = __expf(e2 - m2); p3 = __expf(e3 - m3);
            }
            lpw[lane] = make_float4(p0, p1, p2, p3);
            lcw[lane] = col;
            float s0 = p0, s1 = p1, s2 = p2, s3 = p3;
#pragma unroll
            for (int off = 1; off < 64; off <<= 1) {
                s0 += __shfl_xor(s0, off); s1 += __shfl_xor(s1, off);
                s2 += __shfl_xor(s2, off); s3 += __shfl_xor(s3, off);
            }
            den0 += s0; den1 += s1; den2 += s2; den3 += s3;
            int csz = end - c; if (csz > 64) csz = 64;
            int cnt = (csz + 3) & ~3;
            for (int j = 0; j < cnt; j += 4) {
                float4 pa = lpw[j],     pb = lpw[j + 1];
                float4 pc = lpw[j + 2], pq = lpw[j + 3];
                int c0i = lcw[j], c1i = lcw[j + 1], c2i = lcw[j + 2], c3i = lcw[j + 3];
                unsigned int v0 = *(const unsigned int*)(hb + (size_t)c0i * 128 + 2 * lane);
                unsigned int v1 = *(const unsigned int*)(hb + (size_t)c1i * 128 + 2 * lane);
                unsigned int v2 = *(const unsigned int*)(hb + (size_t)c2i * 128 + 2 * lane);
                unsigned int v3 = *(const unsigned int*)(hb + (size_t)c3i * 128 + 2 * lane);
                float pA0 = sel4(pa.x, pa.y, pa.z, pa.w, hd);
                float pA1 = sel4(pb.x, pb.y, pb.z, pb.w, hd);
                float pA2 = sel4(pc.x, pc.y, pc.z, pc.w, hd);
                float pA3 = sel4(pq.x, pq.y, pq.z, pq.w, hd);
                acc0 += pA0 * bflo(v0) + pA1 * bflo(v1) + pA2 * bflo(v2) + pA3 * bflo(v3);
                acc1 += pA0 * bfhi(v0) + pA1 * bfhi(v1) + pA2 * bfhi(v2) + pA3 * bfhi(v3);
            }
        }
    }

    float dsel = sel4(den0, den1, den2, den3, hd);
    float inv = 1.f / (dsel + 1e-16f);
    float f0 = acc0 * inv;
    float f1 = acc1 * inv;
    const int fA = lane * 2;
    float2 bb  = *(const float2*)(b + fA);
    float2 gg  = *(const float2*)(g + fA);
    float2 be  = *(const float2*)(beta + fA);
    float2 rmm = *(const float2*)(rm + fA);
    float2 rvv = *(const float2*)(rv + fA);
    f0 = (f0 + bb.x - rmm.x) * rsqrtf(rvv.x + BN_EPS) * gg.x + be.x;
    f1 = (f1 + bb.y - rmm.y) * rsqrtf(rvv.y + BN_EPS) * gg.y + be.y;
    f0 = f0 > 0.f ? f0 : (__expf(f0) - 1.f);
    f1 = f1 > 0.f ? f1 : (__expf(f1) - 1.f);
    *(float2*)(obuf + (size_t)n * 128 + fA) = make_float2(f0, f1);
}

// layer2: 1 head, C=32. 8 edges/iter (4 per half), folded at end.
__global__ __launch_bounds__(256) void k_agg2(const float* __restrict__ h,
                                              const float* __restrict__ a_s,
                                              const float* __restrict__ a_d,
                                              const int* __restrict__ row_ptr,
                                              const int* __restrict__ col_idx,
                                              const float* __restrict__ b,
                                              const float* __restrict__ g,
                                              const float* __restrict__ beta,
                                              const float* __restrict__ rm,
                                              const float* __restrict__ rv,
                                              float* __restrict__ obuf) {
    __shared__ float lp[4 * 64];
    __shared__ int   lc[4 * 64];
    const int wid  = threadIdx.x >> 6;
    const int lane = threadIdx.x & 63;
    const int n = (blockIdx.x << 2) + wid;
    if (n >= N_NODES) return;
    float* lpw = lp + (wid << 6);
    int*   lcw = lc + (wid << 6);
    const int l31 = lane & 31, hh = lane >> 5;
    const float ad = a_d[n];
    const int beg = row_ptr[n], end = row_ptr[n + 1];
    const int deg = end - beg;
    float den = 0.f, acc = 0.f;

    if (deg <= 64) {
        const int idx = beg + lane;
        const bool v = idx < end;
        const int col = v ? col_idx[idx] : 0;
        float e = NINF;
        if (v) {
            e = a_s[col] + ad;
            e = e > 0.f ? e : NEG_SLOPE * e;
        }
        float m = e;
#pragma unroll
        for (int off = 1; off < 64; off <<= 1) m = fmaxf(m, __shfl_xor(m, off));
        float p = __expf(e - m);
        lpw[lane] = p;
        lcw[lane] = col;
        den = p;
#pragma unroll
        for (int off = 1; off < 64; off <<= 1) den += __shfl_xor(den, off);
        const int cnt = (deg + 7) & ~7;
        for (int j = 0; j < cnt; j += 8) {
            int j0 = j + (hh << 2);
            float p0 = lpw[j0], p1 = lpw[j0 + 1], p2 = lpw[j0 + 2], p3 = lpw[j0 + 3];
            int c0 = lcw[j0], c1 = lcw[j0 + 1], c2 = lcw[j0 + 2], c3 = lcw[j0 + 3];
            acc += p0 * h[(size_t)c0 * 32 + l31] + p1 * h[(size_t)c1 * 32 + l31]
                 + p2 * h[(size_t)c2 * 32 + l31] + p3 * h[(size_t)c3 * 32 + l31];
        }
    } else {
        float m = NINF;
        for (int c = beg; c < end; c += 64) {
            int idx = c + lane;
            if (idx < end) {
                float e = a_s[col_idx[idx]] + ad;
                e = e > 0.f ? e : NEG_SLOPE * e;
                m = fmaxf(m, e);
            }
        }
#pragma unroll
        for (int off = 1; off < 64; off <<= 1) m = fmaxf(m, __shfl_xor(m, off));
        for (int c = beg; c < end; c += 64) {
            int idx = c + lane;
            bool v = idx < end;
            int col = v ? col_idx[idx] : 0;
            float p = 0.f;
            if (v) {
                float e = a_s[col] + ad;
                e = e > 0.f ? e : NEG_SLOPE * e;
                p = __expf(e - m);
            }
            lpw[lane] = p;
            lcw[lane] = col;
            float s = p;
#pragma unroll
            for (int off = 1; off < 64; off <<= 1) s += __shfl_xor(s, off);
            den += s;
            int csz = end - c; if (csz > 64) csz = 64;
            int cnt = (csz + 7) & ~7;
            for (int j = 0; j < cnt; j += 8) {
                int j0 = j + (hh << 2);
                float p0 = lpw[j0], p1 = lpw[j0 + 1], p2 = lpw[j0 + 2], p3 = lpw[j0 + 3];
                int c0 = lcw[j0], c1 = lcw[j0 + 1], c2 = lcw[j0 + 2], c3 = lcw[j0 + 3];
                acc += p0 * h[(size_t)c0 * 32 + l31] + p1 * h[(size_t)c1 * 32 + l31]
                     + p2 * h[(size_t)c2 * 32 + l31] + p3 * h[(size_t)c3 * 32 + l31];
            }
        }
    }
    acc += __shfl_xor(acc, 32);
    float vout = acc / (den + 1e-16f);
    vout += b[l31];
    vout = (vout - rm[l31]) * rsqrtf(rv[l31] + BN_EPS) * g[l31] + beta[l31];
    vout = vout > 0.f ? vout : (__expf(vout) - 1.f);
    if (lane < 32) obuf[(size_t)n * 32 + lane] = vout;
}

// layer3: 1 head, C=40. fused bias + log_softmax.
__global__ __launch_bounds__(256) void k_agg3(const float* __restrict__ h,
                                              const float* __restrict__ a_s,
                                              const float* __restrict__ a_d,
                                              const int* __restrict__ row_ptr,
                                              const int* __restrict__ col_idx,
                                              const float* __restrict__ b,
                                              float* __restrict__ out) {
    __shared__ float lp[4 * 64];
    __shared__ int   lc[4 * 64];
    const int wid  = threadIdx.x >> 6;
    const int lane = threadIdx.x & 63;
    const int n = (blockIdx.x << 2) + wid;
    if (n >= N_NODES) return;
    float* lpw = lp + (wid << 6);
    int*   lcw = lc + (wid << 6);
    const float ad = a_d[n];
    const int beg = row_ptr[n], end = row_ptr[n + 1];
    const int deg = end - beg;
    float den = 0.f, acc = 0.f;

    if (deg <= 64) {
        const int idx = beg + lane;
        const bool v = idx < end;
        const int col = v ? col_idx[idx] : 0;
        float e = NINF;
        if (v) {
            e = a_s[col] + ad;
            e = e > 0.f ? e : NEG_SLOPE * e;
        }
        float m = e;
#pragma unroll
        for (int off = 1; off < 64; off <<= 1) m = fmaxf(m, __shfl_xor(m, off));
        float p = __expf(e - m);
        lpw[lane] = p;
        lcw[lane] = col;
        den = p;
#pragma unroll
        for (int off = 1; off < 64; off <<= 1) den += __shfl_xor(den, off);
        const int cnt = (deg + 3) & ~3;
        for (int j = 0; j < cnt; j += 4) {
            float p0 = lpw[j], p1 = lpw[j + 1], p2 = lpw[j + 2], p3 = lpw[j + 3];
            int c0 = lcw[j], c1 = lcw[j + 1], c2 = lcw[j + 2], c3 = lcw[j + 3];
            if (lane < 40) {
                acc += p0 * h[(size_t)c0 * 40 + lane] + p1 * h[(size_t)c1 * 40 + lane]
                     + p2 * h[(size_t)c2 * 40 + lane] + p3 * h[(size_t)c3 * 40 + lane];
            }
        }
    } else {
        float m = NINF;
        for (int c = beg; c < end; c += 64) {
            int idx = c + lane;
            if (idx < end) {
                float e = a_s[col_idx[idx]] + ad;
                e = e > 0.f ? e : NEG_SLOPE * e;
                m = fmaxf(m, e);
            }
        }
#pragma unroll
        for (int off = 1; off < 64; off <<= 1) m = fmaxf(m, __shfl_xor(m, off));
        for (int c = beg; c < end; c += 64) {
            int idx = c + lane;
            bool v = idx < end;
            int col = v ? col_idx[idx] : 0;
            float p = 0.f;
            if (v) {
                float e = a_s[col] + ad;
                e = e > 0.f ? e : NEG_SLOPE * e;
                p = __expf(e - m);
            }
            lpw[lane] = p;
            lcw[lane] = col;
            float s = p;
#pragma unroll
            for (int off = 1; off < 64; off <<= 1) s += __shfl_xor(s, off);
            den += s;
            int csz = end - c; if (csz > 64) csz = 64;
            int cnt = (csz + 3) & ~3;
            for (int j = 0; j < cnt; j += 4) {
                float p0 = lpw[j], p1 = lpw[j + 1], p2 = lpw[j + 2], p3 = lpw[j + 3];
                int c0 = lcw[j], c1 = lcw[j + 1], c2 = lcw[j + 2], c3 = lcw[j + 3];
                if (lane < 40) {
                    acc += p0 * h[(size_t)c0 * 40 + lane] + p1 * h[(size_t)c1 * 40 + lane]
                         + p2 * h[(size_t)c2 * 40 + lane] + p3 * h[(size_t)c3 * 40 + lane];
                }
            }
        }
    }
    float vv = acc / (den + 1e-16f) + b[lane < 40 ? lane : 0];
    float vm = (lane < 40) ? vv : NINF;
#pragma unroll
    for (int off = 1; off < 64; off <<= 1) vm = fmaxf(vm, __shfl_xor(vm, off));
    float ex = (lane < 40) ? __expf(vv - vm) : 0.f;
#pragma unroll
    for (int off = 1; off < 64; off <<= 1) ex += __shfl_xor(ex, off);
    float res = vv - vm - logf(ex);
    if (lane < 40) out[(size_t)n * 40 + lane] = res;
}

// ---------------------------------------------------------------- launch

extern "C" void kernel_launch(void* const* d_in, const int* in_sizes, int n_in,
                              void* d_out, int out_size, void* d_ws, size_t ws_size,
                              hipStream_t stream) {
    const float* x    = (const float*)d_in[0];
    const int*   ei   = (const int*)d_in[1];
    const float* W1   = (const float*)d_in[2];
    const float* as1  = (const float*)d_in[3];
    const float* ad1  = (const float*)d_in[4];
    const float* b1   = (const float*)d_in[5];
    const float* g1   = (const float*)d_in[6];
    const float* be1  = (const float*)d_in[7];
    const float* rm1  = (const float*)d_in[8];
    const float* rv1  = (const float*)d_in[9];
    const float* W2   = (const float*)d_in[10];
    const float* as2  = (const float*)d_in[11];
    const float* ad2  = (const float*)d_in[12];
    const float* b2   = (const float*)d_in[13];
    const float* g2   = (const float*)d_in[14];
    const float* be2  = (const float*)d_in[15];
    const float* rm2  = (const float*)d_in[16];
    const float* rv2  = (const float*)d_in[17];
    const float* W3   = (const float*)d_in[18];
    const float* as3  = (const float*)d_in[19];
    const float* ad3  = (const float*)d_in[20];
    const float* b3   = (const float*)d_in[21];
    float* out = (float*)d_out;

    char* base = (char*)d_ws;
    size_t off = 0;
    auto carve = [&](size_t bytes) {
        char* p = base + off;
        off = (off + bytes + 255) & ~(size_t)255;
        return p;
    };
    int*   row_ptr  = (int*)carve((N_NODES + 1) * sizeof(int));
    int*   cnt      = (int*)carve(N_NODES * sizeof(int));
    int*   sums     = (int*)carve(1024 * sizeof(int));
    int*   bucket_cnt    = (int*)carve((NBUCK + 1) * sizeof(int));
    int*   bucket_base   = (int*)carve((NBUCK + 1) * sizeof(int));
    int*   bucket_cursor = (int*)carve((NBUCK + 1) * sizeof(int));
    int*   col_idx  = (int*)carve((size_t)E_TOT * sizeof(int));
    unsigned int* estage = (unsigned int*)carve((size_t)E_TOT * sizeof(unsigned int));
    float* a_s      = (float*)carve((size_t)N_NODES * 4 * sizeof(float));
    float* a_d      = (float*)carve((size_t)N_NODES * 4 * sizeof(float));
    float* hbuf     = (float*)carve((size_t)N_NODES * 128 * sizeof(float));
    float* obuf     = (float*)carve((size_t)N_NODES * 128 * sizeof(float));
    (void)ws_size;

    hipMemsetAsync(cnt, 0, N_NODES * sizeof(int), stream);
    hipMemsetAsync(bucket_cnt, 0, (NBUCK + 1) * sizeof(int), stream);
    {
        // row_ptr (degree count + scan)
        int g1b = (E_TOT + 255) / 256;
        k_count<<<g1b, 256, 0, stream>>>(ei, cnt);
        int nb = (N_NODES + 1023) / 1024;
        k_scan1<<<nb, 256, 0, stream>>>(cnt, row_ptr, sums);
        k_scan2<<<1, 1, 0, stream>>>(sums, nb);
        k_scan3<<<(N_NODES + 255) / 256, 256, 0, stream>>>(row_ptr, sums);
        // binned col_idx scatter
        int gsb = (E_TOT + EPB - 1) / EPB;
        kb_hist<<<gsb, 256, 0, stream>>>(ei, bucket_cnt);
        kb_scan<<<1, 1, 0, stream>>>(bucket_cnt, bucket_base, bucket_cursor);
        kb_stage<<<gsb, 256, 0, stream>>>(ei, bucket_cursor, estage);
        kb_scatter<<<NBUCK, 256, 0, stream>>>(estage, bucket_base, row_ptr, col_idx);
    }

    const int GEMM_GRID = (N_NODES + 63) / 64;
    const int WPN = (N_NODES + 3) / 4;

    // layer1: GEMM + fused attproj (4 heads), bf16 h for the gather
    k_gemm_ap<128, 128, 64, 256, 4, true><<<GEMM_GRID, 256, 0, stream>>>(
        x, W1, as1, ad1, a_s, a_d, (void*)hbuf, N_NODES);
    k_agg1<<<WPN, 256, 0, stream>>>((const unsigned short*)hbuf, a_s, a_d,
                                    row_ptr, col_idx,
                                    b1, g1, be1, rm1, rv1, obuf);

    // layer2: GEMM + fused attproj (1 head), fp32 h
    k_gemm_ap<128, 32, 64, 256, 1, false><<<GEMM_GRID, 256, 0, stream>>>(
        obuf, W2, as2, ad2, a_s, a_d, (void*)hbuf, N_NODES);
    k_agg2<<<WPN, 256, 0, stream>>>(hbuf, a_s, a_d, row_ptr, col_idx,
                                    b2, g2, be2, rm2, rv2, obuf);

    // layer3: plain GEMM (40 cols)
    k_gemm<32, 40, 64, 320><<<GEMM_GRID, 320, 0, stream>>>(obuf, W3, hbuf, N_NODES);
    k_attproj3<<<WPN, 256, 0, stream>>>(hbuf, as3, ad3, a_s, a_d);
    k_agg3<<<WPN, 256, 0, stream>>>(hbuf, a_s, a_d, row_ptr, col_idx, b3, out);
}